// Round 9
// baseline (427.429 us; speedup 1.0000x reference)
//
#include <hip/hip_runtime.h>
#include <cmath>

typedef unsigned short ush;  // bf16 raw bits
typedef __attribute__((ext_vector_type(8))) short short8;
typedef __attribute__((ext_vector_type(4))) float floatx4;

static constexpr int N_P = 100000, N_D = 1000, N_S = 5000, NT = N_P + N_D + N_S;
static constexpr int NC = 111000;  // concatenated dst slots: r0:1000 | r1:100000 | r2:5000 | r3:5000
static constexpr int E_TOT = 800000;

// hist-CSR geometry
static constexpr int NB0 = 128, NB2 = 64, NB3 = 64;
static constexpr int CH0 = (300000 + NB0 - 1) / NB0;  // 2344
static constexpr int CH2 = (100000 + NB2 - 1) / NB2;  // 1563
static constexpr int HB0_OFF = 0;
static constexpr int HB2_OFF = NB0 * 1000;            // 128000
static constexpr int HB3_OFF = HB2_OFF + NB2 * 5000;  // 448000 -> total 768000
static constexpr int NCH0 = NB0 / 16, NCH2 = NB2 / 16;  // 8, 4
static constexpr int CS0_OFF = 0;
static constexpr int CS2_OFF = NCH0 * 1000;            // 8000
static constexpr int CS3_OFF = CS2_OFF + NCH2 * 5000;  // 28000 -> total 48000
static constexpr int NHIST = NB0 + NB2 + NB3;          // 256
static constexpr int NBLK_R1 = (300000 + 255) / 256;   // 1172
static constexpr int NZB = (100000 + 255) / 256;       // 391

__device__ __forceinline__ float b2f(ush b) { return __uint_as_float(((unsigned)b) << 16); }
__device__ __forceinline__ ush f2b(float f) {
    unsigned u = __float_as_uint(f);
    return (ush)((u + 0x7FFFu + ((u >> 16) & 1u)) >> 16);
}
// load element i of a raw tensor, rounded to bf16 exactly as the CW convert does
__device__ __forceinline__ float ldr(const void* p, int fl, long i) {
    return fl ? b2f(f2b(((const float*)p)[i])) : b2f(((const ush*)p)[i]);
}

// canonical weight-block offsets (bf16 elements), d_in[3..20]
static constexpr size_t OFF_WINP = 0;
static constexpr size_t OFF_BINP = 4096;
static constexpr size_t OFF_WIND = 4160;
static constexpr size_t OFF_BIND = 12352;
static constexpr size_t OFF_WINS = 12416;
static constexpr size_t OFF_BINS = 16512;
static constexpr size_t OFF_WK = 16576;
static constexpr size_t OFF_BK = 41152;
static constexpr size_t OFF_WQ = 41536;
static constexpr size_t OFF_BQ = 66112;
static constexpr size_t OFF_WV = 66496;
static constexpr size_t OFF_BV = 91072;
static constexpr size_t OFF_WA = 91456;
static constexpr size_t OFF_BA = 116032;
static constexpr size_t OFF_AREL = 116416;
static constexpr size_t OFF_MREL = 124608;
static constexpr size_t OFF_PREL = 132800;
static constexpr size_t OFF_SKIP = 132832;
static constexpr size_t CW_TOTAL = 132838;
static constexpr int NCONVB = (int)((CW_TOTAL + 255) / 256);  // 519
static constexpr int NSCB = (NC + 1 + 255) / 256;             // 434

// fragment-layout weight buffer (ush elements)
static constexpr size_t TWINP = 0;      // 4096  (64x64)
static constexpr size_t TWIND = 4096;   // 8192  (128x64)
static constexpr size_t TWINS = 12288;  // 4096
static constexpr size_t TWQO = 16384;   // 6*4096 (l*3+t)
static constexpr size_t TWAO = 40960;   // 6*4096
static constexpr size_t TW_TOTAL = 65536;
static constexpr int NTWB = (int)(TW_TOTAL / 256);  // 256

struct ConvArgs {
    const void* src[18];
    long cum[19];
    int fl[18];  // 1 = fp32 source, 0 = bf16 source (host-derived from in_sizes)
};

struct CsrB {
    const int* ei[3];  // r0, r2, r3 edge arrays
    const int* ei1;    // r1
};

__device__ __forceinline__ void hist_geom(int b, const CsrB& c, int& r, const int*& ei, int& E,
                                          int& ndst, int& e0, int& e1, int& hb) {
    if (b < NB0) {
        r = 0; ei = c.ei[0]; E = 300000; ndst = 1000;
        e0 = b * CH0; hb = HB0_OFF + b * 1000;
    } else if (b < NB0 + NB2) {
        r = 1; ei = c.ei[1]; E = 100000; ndst = 5000;
        e0 = (b - NB0) * CH2; hb = HB2_OFF + (b - NB0) * 5000;
    } else {
        r = 2; ei = c.ei[2]; E = 100000; ndst = 5000;
        e0 = (b - NB0 - NB2) * CH2; hb = HB3_OFF + (b - NB0 - NB2) * 5000;
    }
    e1 = min(E, e0 + ((r == 0) ? CH0 : CH2));
}

__device__ __forceinline__ bool cs_geom(int g, int& idx0, int& step) {
    if (g >= 48000) return false;
    if (g < 8000) {
        int c = g / 1000, d = g % 1000;
        idx0 = HB0_OFF + c * 16 * 1000 + d; step = 1000;
    } else if (g < 28000) {
        int gg = g - 8000, c = gg / 5000, d = gg % 5000;
        idx0 = HB2_OFF + c * 16 * 5000 + d; step = 5000;
    } else {
        int gg = g - 28000, c = gg / 5000, d = gg % 5000;
        idx0 = HB3_OFF + c * 16 * 5000 + d; step = 5000;
    }
    return true;
}

// ---------------------------------------------------------------------------
// K1: convert weights | zero CNT r1 | histograms | fragment transposes |
//     eff K|V weight folding (from raw inputs, bf16-rounded == CW values).
// ---------------------------------------------------------------------------
__global__ __launch_bounds__(256) void k1_kernel(ConvArgs a, ush* __restrict__ dst,
                                                 ush* __restrict__ tw,
                                                 int* __restrict__ cnt_r1, CsrB c,
                                                 int* __restrict__ HB,
                                                 ush* __restrict__ weff) {
    const int b = blockIdx.x;
    if (b < NCONVB) {
        long g = (long)b * 256 + threadIdx.x;
        if (g >= (long)CW_TOTAL) return;
        int t = 0;
        while (g >= a.cum[t + 1]) t++;
        long i = g - a.cum[t];
        float v = a.fl[t] ? ((const float*)a.src[t])[i] : b2f(((const ush*)a.src[t])[i]);
        dst[g] = f2b(v);
    } else if (b < NCONVB + NZB) {
        int g = (b - NCONVB) * 256 + threadIdx.x;
        if (g < 100000) cnt_r1[g] = 0;
    } else if (b < NCONVB + NZB + NHIST) {
        __shared__ int h[5000];
        int r, E, ndst, e0, e1, hb;
        const int* ei;
        hist_geom(b - NCONVB - NZB, c, r, ei, E, ndst, e0, e1, hb);
        for (int d = threadIdx.x; d < ndst; d += 256) h[d] = 0;
        __syncthreads();
        for (int e = e0 + threadIdx.x; e < e1; e += 256) atomicAdd(&h[ei[E + e]], 1);
        __syncthreads();
        for (int d = threadIdx.x; d < ndst; d += 256) HB[hb + d] = h[d];
    } else if (b < NCONVB + NZB + NHIST + NTWB) {
        int g = (b - NCONVB - NZB - NHIST) * 256 + threadIdx.x;  // [0, 65536)
        const void* src; int fl; long ibase; int e;
        if (g < 4096) { src = a.src[0]; fl = a.fl[0]; e = g; ibase = 0; }
        else if (g < 12288) { src = a.src[2]; fl = a.fl[2]; e = g - 4096; ibase = 0; }
        else if (g < 16384) { src = a.src[4]; fl = a.fl[4]; e = g - 12288; ibase = 0; }
        else if (g < 40960) { int ee = g - 16384; src = a.src[8]; fl = a.fl[8];
                              e = ee & 4095; ibase = (long)(ee >> 12) * 4096; }
        else { int ee = g - 40960; src = a.src[12]; fl = a.fl[12];
               e = ee & 4095; ibase = (long)(ee >> 12) * 4096; }
        int f = e >> 9, l = (e >> 3) & 63, j = e & 7;
        int s = f >> 2, cc = f & 3;
        long in = ibase + (long)(32 * s + ((l >> 4) << 3) + j) * 64 + 16 * cc + (l & 15);
        float v = fl ? ((const float*)src)[in] : b2f(((const ush*)src)[in]);
        tw[g] = f2b(v);
    } else {
        const int eb = b - NCONVB - NZB - NHIST - NTWB;  // l*4+r
        const int l = eb >> 2, r = eb & 3;
        const int st_of[4] = {0, 1, 1, 0};
        const int st = st_of[r];
        ush* out = weff + (size_t)eb * 8320;
        for (int idx = threadIdx.x; idx < 8320; idx += 256) {
            int k, n;
            if (idx < 8192) {
                int f = idx >> 9, ll = (idx >> 3) & 63, j = idx & 7;
                int s = f >> 3, cc = f & 7;
                k = 32 * s + ((ll >> 4) << 3) + j;
                n = 16 * cc + (ll & 15);
            } else { k = -1; n = idx - 8192; }
            int kv = n >= 64;
            int jj = n & 63, h = jj >> 4, e = jj & 15;
            const void* Wp = kv ? a.src[10] : a.src[6];
            const int flW = kv ? a.fl[10] : a.fl[6];
            const void* Bp = kv ? a.src[11] : a.src[7];
            const int flB = kv ? a.fl[11] : a.fl[7];
            const void* Rp = kv ? a.src[15] : a.src[14];
            const int flR = kv ? a.fl[15] : a.fl[14];
            const long wb = (long)(l * 3 + st) * 4096;
            const long bb = (long)(l * 3 + st) * 64;
            const long rb = (long)(l * 4 + r) * 1024;
            float acc = 0.f;
            if (k >= 0) {
#pragma unroll
                for (int d = 0; d < 16; d++)
                    acc += ldr(Wp, flW, wb + k * 64 + h * 16 + d) *
                           ldr(Rp, flR, rb + h * 256 + d * 16 + e);
            } else {
#pragma unroll
                for (int d = 0; d < 16; d++)
                    acc += ldr(Bp, flB, bb + h * 16 + d) *
                           ldr(Rp, flR, rb + h * 256 + d * 16 + e);
            }
            out[idx] = f2b(acc);
        }
    }
}

// ---------------------------------------------------------------------------
// MFMA building blocks.
// ---------------------------------------------------------------------------
template <int K>
__device__ __forceinline__ void stage_A_raw(short* sA, const void* __restrict__ X, int f,
                                            int M, int row0) {
    for (int cid = threadIdx.x; cid < 64 * K / 8; cid += 256) {
        int r = cid / (K / 8), c0 = (cid % (K / 8)) * 8;
        int row = row0 + r;
        short8 v = {0, 0, 0, 0, 0, 0, 0, 0};
        if (row < M) {
            if (f) {
                const floatx4* fp = (const floatx4*)((const float*)X + (size_t)row * K + c0);
                floatx4 f0 = fp[0], f1 = fp[1];
#pragma unroll
                for (int j = 0; j < 4; j++) v[j] = (short)f2b(f0[j]);
#pragma unroll
                for (int j = 0; j < 4; j++) v[4 + j] = (short)f2b(f1[j]);
            } else {
                v = *(const short8*)(const void*)((const ush*)X + (size_t)row * K + c0);
            }
        }
        *(short8*)(&sA[r * (K + 8) + c0]) = v;
    }
}

// stage a 64-col half of a [M][128] raw tensor into sA (stride 72)
__device__ __forceinline__ void stage_A_half(short* sA, const void* __restrict__ X, int f,
                                             int M, int row0, int half) {
    for (int cid = threadIdx.x; cid < 512; cid += 256) {
        int r = cid >> 3, c0 = (cid & 7) * 8;
        int row = row0 + r;
        short8 v = {0, 0, 0, 0, 0, 0, 0, 0};
        if (row < M) {
            long off = (long)row * 128 + half * 64 + c0;
            if (f) {
                const floatx4* fp = (const floatx4*)((const float*)X + off);
                floatx4 f0 = fp[0], f1 = fp[1];
#pragma unroll
                for (int j = 0; j < 4; j++) v[j] = (short)f2b(f0[j]);
#pragma unroll
                for (int j = 0; j < 4; j++) v[4 + j] = (short)f2b(f1[j]);
            } else {
                v = *(const short8*)(const void*)((const ush*)X + off);
            }
        }
        *(short8*)(&sA[r * 72 + c0]) = v;
    }
}

// one K=64 MFMA pass: A from sA (stride 72), B frags from sB, accumulate.
__device__ __forceinline__ void mfma64_acc(const short* sA, const short* sB, floatx4* acc) {
    const int tid = threadIdx.x;
    const int w = tid >> 6, l = tid & 63;
#pragma unroll
    for (int s = 0; s < 2; s++) {
        short8 av = *(const short8*)(&sA[(16 * w + (l & 15)) * 72 + 32 * s + ((l >> 4) << 3)]);
#pragma unroll
        for (int c = 0; c < 4; c++) {
            short8 bv = *(const short8*)(&sB[(s * 4 + c) * 512 + l * 8]);
            acc[c] = __builtin_amdgcn_mfma_f32_16x16x32_bf16(av, bv, acc[c], 0, 0, 0);
        }
    }
}

// ---------------------------------------------------------------------------
// 5-panel streaming QKV gemm: A-fragments in registers (sA freed -> output
// stage), per panel {stage 8KB B, 8 MFMAs, scatter, coalesced store}.
// Panels: 0=Q, 1=relA.K, 2=relA.V, 3=relB.K, 4=relB.V (all ld-64).
// ---------------------------------------------------------------------------
template <int NP>
__device__ __forceinline__ void gemm_panels(short* sA, short* sB,
                                            const ush* __restrict__ Wq,
                                            const ush* __restrict__ Bq, ush* __restrict__ Yq,
                                            const ush* __restrict__ WeA,
                                            ush* __restrict__ YAk, ush* __restrict__ YAv,
                                            const ush* __restrict__ WeB,
                                            ush* __restrict__ YBk, ush* __restrict__ YBv,
                                            int M, int row0) {
    const int tid = threadIdx.x;
    const int w = tid >> 6, l = tid & 63;
    __syncthreads();  // X-tile in sA visible
    short8 a0 = *(const short8*)(&sA[(16 * w + (l & 15)) * 72 + ((l >> 4) << 3)]);
    short8 a1 = *(const short8*)(&sA[(16 * w + (l & 15)) * 72 + 32 + ((l >> 4) << 3)]);
    ush* dst[5] = {Yq, YAk, YAv, YBk, YBv};
#pragma unroll
    for (int p = 0; p < NP; p++) {
        __syncthreads();  // prev MFMA done with sB; prev store done with sA-out; a-regs loaded
        const ush* base = (p == 0) ? Wq : ((p <= 2) ? WeA : WeB);
        const int nw = (p == 0) ? 4 : 8;
        const int moff = (p == 0 || p == 1 || p == 3) ? 0 : 4;
        for (int u = tid; u < 512; u += 256) {
            int f = u >> 6, k = u & 63;  // f = s*4 + c
            int s = f >> 2, c = f & 3;
            const ush* src = base + (size_t)(s * nw + moff + c) * 512;
            *(short8*)(&sB[f * 512 + k * 8]) = *(const short8*)(const void*)(src + k * 8);
        }
        __syncthreads();
        const ush* bias = (p == 0) ? Bq : ((p <= 2) ? WeA + 8192 : WeB + 8192);
        const int boff = (p == 0 || p == 1 || p == 3) ? 0 : 64;
        floatx4 acc[4];
#pragma unroll
        for (int c = 0; c < 4; c++) {
            float bv = b2f(bias[boff + 16 * c + (l & 15)]);
            acc[c] = (floatx4){bv, bv, bv, bv};
        }
#pragma unroll
        for (int c = 0; c < 4; c++) {
            short8 b0 = *(const short8*)(&sB[c * 512 + l * 8]);
            acc[c] = __builtin_amdgcn_mfma_f32_16x16x32_bf16(a0, b0, acc[c], 0, 0, 0);
            short8 b1 = *(const short8*)(&sB[(4 + c) * 512 + l * 8]);
            acc[c] = __builtin_amdgcn_mfma_f32_16x16x32_bf16(a1, b1, acc[c], 0, 0, 0);
        }
#pragma unroll
        for (int c = 0; c < 4; c++)
#pragma unroll
            for (int r = 0; r < 4; r++)
                sA[(16 * w + ((l >> 4) << 2) + r) * 72 + 16 * c + (l & 15)] =
                    (short)f2b(acc[c][r]);
        __syncthreads();
        ush* Y = dst[p];
        for (int u = tid; u < 512; u += 256) {
            int r = u >> 3, c0 = (u & 7) * 8;
            int row = row0 + r;
            if (row < M)
                *(short8*)(Y + (size_t)row * 64 + c0) = *(const short8*)(&sA[r * 72 + c0]);
        }
    }
}

__device__ __forceinline__ void run_panels(int t, short* sA, short* sB,
                                           const ush* const* Wq, const ush* const* Bq,
                                           const ush* const* We, ush* Q,
                                           ush* const* KVk, ush* const* KVv,
                                           int M, int row0) {
    if (t == 0)
        gemm_panels<5>(sA, sB, Wq[0], Bq[0], Q, We[0], KVk[0], KVv[0],
                       We[3], KVk[3], KVv[3], M, row0);
    else if (t == 1)
        gemm_panels<5>(sA, sB, Wq[1], Bq[1], Q + (size_t)N_P * 64, We[1], KVk[1], KVv[1],
                       We[2], KVk[2], KVv[2], M, row0);
    else
        gemm_panels<1>(sA, sB, Wq[2], Bq[2], Q + (size_t)(N_P + N_D) * 64,
                       nullptr, nullptr, nullptr, nullptr, nullptr, nullptr, M, row0);
}

// ---------------------------------------------------------------------------
// K2F: fused input projections + layer-0 Q/KV panels | chunk-scan | r1 counts.
// Dyn LDS: sA 9216 + sB 8192 = 17408 B (D's K=128 done as two K=64 halves).
// ---------------------------------------------------------------------------
struct K2FArgs {
    const void* raw[3];
    int f[3];
    const ush* Wi[3];  // inproj fragment weights (TW)
    const ush* Bi[3];  // inproj biases (CW)
    ush* X;
    const ush* Wq[3];  // layer-0 Q fragment weights (TW)
    const ush* Bq[3];
    const ush* We[4];  // layer-0 eff fragment weights (weff)
    ush* Q;
    ush* KVk[4];
    ush* KVv[4];
    const int* HB;
    int* CS;
    int* cnt;
    const int* ei1;
};

__global__ __launch_bounds__(256) void k2f_kernel(K2FArgs a) {
    extern __shared__ short smem[];
    const int b = blockIdx.x;
    if (b < 1658) {
        short* sA = smem;
        short* sB = smem + 64 * 72;
        const int tid = threadIdx.x;
        const int w = tid >> 6, l = tid & 63;
        int t, lb, M;
        if (b < 1563) { t = 0; lb = b; M = N_P; }
        else if (b < 1579) { t = 1; lb = b - 1563; M = N_D; }
        else { t = 2; lb = b - 1579; M = N_S; }
        const size_t noff = (t == 0) ? 0 : (t == 1) ? (size_t)N_P : (size_t)(N_P + N_D);
        const int row0 = lb * 64;
        floatx4 acc[4];
#pragma unroll
        for (int c = 0; c < 4; c++) {
            float bv = b2f(a.Bi[t][16 * c + (l & 15)]);
            acc[c] = (floatx4){bv, bv, bv, bv};
        }
        if (t != 1) {
            stage_A_raw<64>(sA, a.raw[t], a.f[t], M, row0);
            for (int u = tid; u < 512; u += 256)
                *(short8*)(&sB[u * 8]) = *(const short8*)(const void*)(a.Wi[t] + (size_t)u * 8);
            __syncthreads();
            mfma64_acc(sA, sB, acc);
        } else {
#pragma unroll
            for (int hh = 0; hh < 2; hh++) {
                if (hh) __syncthreads();  // prev MFMA reads done before restage
                stage_A_half(sA, a.raw[1], a.f[1], M, row0, hh);
                for (int u = tid; u < 512; u += 256)
                    *(short8*)(&sB[u * 8]) =
                        *(const short8*)(const void*)(a.Wi[1] + (size_t)hh * 4096 + (size_t)u * 8);
                __syncthreads();
                mfma64_acc(sA, sB, acc);
            }
        }
        __syncthreads();
        // scatter X tile into sA (72-stride)
#pragma unroll
        for (int c = 0; c < 4; c++)
#pragma unroll
            for (int r = 0; r < 4; r++)
                sA[(16 * w + ((l >> 4) << 2) + r) * 72 + 16 * c + (l & 15)] =
                    (short)f2b(acc[c][r]);
        __syncthreads();
        ush* Xb = a.X + noff * 64;
        for (int u = tid; u < 512; u += 256) {
            int r = u >> 3, c0 = (u & 7) * 8;
            int row = row0 + r;
            if (row < M)
                *(short8*)(Xb + (size_t)row * 64 + c0) = *(const short8*)(&sA[r * 72 + c0]);
        }
        run_panels(t, sA, sB, a.Wq, a.Bq, a.We, a.Q, a.KVk, a.KVv, M, row0);
    } else if (b < 1701) {
        int d = (b - 1658) * 256 + threadIdx.x;
        if (d >= 11000) return;
        int ld_, nch, base, step, cs0, csstep, roff;
        if (d < 1000) { ld_ = d; nch = NCH0; base = HB0_OFF + ld_; step = 1000;
                        cs0 = CS0_OFF + ld_; csstep = 1000; roff = 0; }
        else if (d < 6000) { ld_ = d - 1000; nch = NCH2; base = HB2_OFF + ld_; step = 5000;
                             cs0 = CS2_OFF + ld_; csstep = 5000; roff = 101000; }
        else { ld_ = d - 6000; nch = NCH2; base = HB3_OFF + ld_; step = 5000;
               cs0 = CS3_OFF + ld_; csstep = 5000; roff = 106000; }
        int run = 0;
        for (int cc = 0; cc < nch; cc++) {
            int s = 0;
#pragma unroll
            for (int bb = 0; bb < 16; bb++) s += a.HB[base + (cc * 16 + bb) * step];
            a.CS[cs0 + cc * csstep] = run;
            run += s;
        }
        a.cnt[roff + ld_] = run;
    } else {
        int g = (b - 1701) * 256 + threadIdx.x;
        if (g < 300000) atomicAdd(&a.cnt[1000 + a.ei1[300000 + g]], 1);
    }
}

// ---------------------------------------------------------------------------
// K3: scanA (block-local scan + partials) only.
// ---------------------------------------------------------------------------
__global__ __launch_bounds__(256) void k3_kernel(const int* __restrict__ cnt,
                                                 int* __restrict__ tmp,
                                                 int* __restrict__ part) {
    const int b = blockIdx.x;
    __shared__ int ls[256];
    const int t = threadIdx.x;
    const int base = b * 1024 + t * 4;
    int v[4];
#pragma unroll
    for (int j = 0; j < 4; j++) v[j] = (base + j < NC) ? cnt[base + j] : 0;
    int tsum = v[0] + v[1] + v[2] + v[3];
    ls[t] = tsum;
    __syncthreads();
    for (int off = 1; off < 256; off <<= 1) {
        int y = (t >= off) ? ls[t - off] : 0;
        __syncthreads();
        ls[t] += y;
        __syncthreads();
    }
    int run = ls[t] - tsum;
#pragma unroll
    for (int j = 0; j < 4; j++) {
        if (base + j < NC) tmp[base + j] = run;
        run += v[j];
    }
    if (t == 255) part[b] = ls[255];
}

// ---------------------------------------------------------------------------
// K4: rowptr (inline partial rescan) | fixHB | zero fillpos.
// ---------------------------------------------------------------------------
__global__ __launch_bounds__(256) void k4_kernel(const int* __restrict__ tmp,
                                                 const int* __restrict__ part,
                                                 int* __restrict__ rowptr,
                                                 int* __restrict__ HB,
                                                 const int* __restrict__ CS,
                                                 int* __restrict__ fillpos) {
    const int b = blockIdx.x;
    if (b < NSCB) {
        __shared__ int ls[256];
        const int t = threadIdx.x;
        ls[t] = (t < 109) ? part[t] : 0;
        __syncthreads();
        for (int off = 1; off < 256; off <<= 1) {
            int y = (t >= off) ? ls[t - off] : 0;
            __syncthreads();
            ls[t] += y;
            __syncthreads();
        }
        int i = b * 256 + t;
        if (i <= NC)
            rowptr[i] = (i == NC) ? ls[255] : tmp[i] + ((i >> 10) ? ls[(i >> 10) - 1] : 0);
    } else if (b < NSCB + 188) {
        int g = (b - NSCB) * 256 + threadIdx.x;
        int idx0, step;
        if (!cs_geom(g, idx0, step)) return;
        int run = CS[g];
#pragma unroll
        for (int bb = 0; bb < 16; bb++) {
            int t2 = HB[idx0 + bb * step];
            HB[idx0 + bb * step] = run;
            run += t2;
        }
    } else {
        int g = (b - NSCB - 188) * 256 + threadIdx.x;
        if (g < 100000) fillpos[g] = 0;
    }
}

// ---------------------------------------------------------------------------
// fill: CSR column fill (layer 0 only). Dyn LDS: 20000 B.
// ---------------------------------------------------------------------------
struct FillArgs {
    CsrB cb;
    const int* HB;
    const int* rowptr;
    int* fillpos;  // == CNT base; kernel indexes fillpos[1000 + dst]
    int* col;
};

__global__ __launch_bounds__(256) void fill_kernel(FillArgs a) {
    extern __shared__ short smem[];
    const int b = blockIdx.x;
    if (b < NHIST) {
        int* h = (int*)smem;
        int r, E, ndst, e0, e1, hb;
        const int* ei;
        hist_geom(b, a.cb, r, ei, E, ndst, e0, e1, hb);
        const int roff = (r == 0) ? 0 : (r == 1) ? 101000 : 106000;
        for (int d = threadIdx.x; d < ndst; d += 256) h[d] = a.rowptr[roff + d] + a.HB[hb + d];
        __syncthreads();
        for (int e = e0 + threadIdx.x; e < e1; e += 256) {
            int d = ei[E + e];
            int slot = atomicAdd(&h[d], 1);
            a.col[slot] = ei[e];
        }
    } else {
        int g = (b - NHIST) * 256 + threadIdx.x;
        if (g < 300000) {
            int gi = 1000 + a.cb.ei1[300000 + g];
            int slot = a.rowptr[gi] + atomicAdd(&a.fillpos[gi], 1);
            a.col[slot] = a.cb.ei1[g];
        }
    }
}

// ---------------------------------------------------------------------------
// Fused gather aggregation; K/V in split half-arrays; writes gelu(out) bf16.
// Fixed per-lane shift softmax (peeled first edge) -> independent iterations;
// unroll-2 software pipeline for MLP.
// ---------------------------------------------------------------------------
struct AggrArgs {
    const int* rowptr;
    const int* col;
    const ush* KVk[4];
    const ush* KVv[4];
    const ush* Q;
    const ush* prel;
    ush* OUT;
};

template <int LANES>
__device__ __forceinline__ void seg_attn(const AggrArgs& a, int rel, int g, int h, int lane,
                                         const float* qf, float* o) {
    const int s0 = a.rowptr[g], s1 = a.rowptr[g + 1];
    const ush* Kb = a.KVk[rel];
    const ush* Vb = a.KVv[rel];
    const float ps = b2f(a.prel[rel * 4 + h]) * 0.25f;
    float m = -1e30f, s = 0.f;
    float acc[16];
#pragma unroll
    for (int i = 0; i < 16; i++) acc[i] = 0.f;
    int j = s0 + lane;
    if (j < s1) {
        {
            int src = a.col[j];
            const ush* kp = Kb + (size_t)src * 64 + h * 16;
            const ush* vp = Vb + (size_t)src * 64 + h * 16;
            short8 k0 = *(const short8*)(const void*)kp;
            short8 k1 = *(const short8*)(const void*)(kp + 8);
            short8 v0 = *(const short8*)(const void*)vp;
            short8 v1 = *(const short8*)(const void*)(vp + 8);
            float dot = 0.f;
#pragma unroll
            for (int i = 0; i < 8; i++) dot += qf[i] * b2f((ush)k0[i]);
#pragma unroll
            for (int i = 0; i < 8; i++) dot += qf[8 + i] * b2f((ush)k1[i]);
            m = dot * ps;
            s = 1.f;
#pragma unroll
            for (int i = 0; i < 8; i++) acc[i] = b2f((ush)v0[i]);
#pragma unroll
            for (int i = 0; i < 8; i++) acc[8 + i] = b2f((ush)v1[i]);
        }
        j += LANES;
        for (; j + LANES < s1; j += 2 * LANES) {
            int srcA = a.col[j];
            int srcB = a.col[j + LANES];
            const ush* kpA = Kb + (size_t)srcA * 64 + h * 16;
            const ush* vpA = Vb + (size_t)srcA * 64 + h * 16;
            const ush* kpB = Kb + (size_t)srcB * 64 + h * 16;
            const ush* vpB = Vb + (size_t)srcB * 64 + h * 16;
            short8 k0A = *(const short8*)(const void*)kpA;
            short8 k1A = *(const short8*)(const void*)(kpA + 8);
            short8 v0A = *(const short8*)(const void*)vpA;
            short8 v1A = *(const short8*)(const void*)(vpA + 8);
            short8 k0B = *(const short8*)(const void*)kpB;
            short8 k1B = *(const short8*)(const void*)(kpB + 8);
            short8 v0B = *(const short8*)(const void*)vpB;
            short8 v1B = *(const short8*)(const void*)(vpB + 8);
            float dotA = 0.f, dotB = 0.f;
#pragma unroll
            for (int i = 0; i < 8; i++) dotA += qf[i] * b2f((ush)k0A[i]);
#pragma unroll
            for (int i = 0; i < 8; i++) dotA += qf[8 + i] * b2f((ush)k1A[i]);
#pragma unroll
            for (int i = 0; i < 8; i++) dotB += qf[i] * b2f((ush)k0B[i]);
#pragma unroll
            for (int i = 0; i < 8; i++) dotB += qf[8 + i] * b2f((ush)k1B[i]);
            float eA = __expf(dotA * ps - m);
            float eB = __expf(dotB * ps - m);
            s += eA + eB;
#pragma unroll
            for (int i = 0; i < 8; i++) acc[i] += eA * b2f((ush)v0A[i]) + eB * b2f((ush)v0B[i]);
#pragma unroll
            for (int i = 0; i < 8; i++)
                acc[8 + i] += eA * b2f((ush)v1A[i]) + eB * b2f((ush)v1B[i]);
        }
        if (j < s1) {
            int src = a.col[j];
            const ush* kp = Kb + (size_t)src * 64 + h * 16;
            const ush* vp = Vb + (size_t)src * 64 + h * 16;
            short8 k0 = *(const short8*)(const void*)kp;
            short8 k1 = *(const short8*)(const void*)(kp + 8);
            short8 v0 = *(const short8*)(const void*)vp;
            short8 v1 = *(const short8*)(const void*)(vp + 8);
            float dot = 0.f;
#pragma unroll
            for (int i = 0; i < 8; i++) dot += qf[i] * b2f((ush)k0[i]);
#pragma unroll
            for (int i = 0; i < 8; i++) dot += qf[8 + i] * b2f((ush)k1[i]);
            float e1 = __expf(dot * ps - m);
            s += e1;
#pragma unroll
            for (int i = 0; i < 8; i++) acc[i] += e1 * b2f((ush)v0[i]);
#pragma unroll
            for (int i = 0; i < 8; i++) acc[8 + i] += e1 * b2f((ush)v1[i]);
        }
    }
#pragma unroll
    for (int wd = LANES >> 1; wd >= 1; wd >>= 1) {
        float mo = __shfl_xor(m, wd);
        float so = __shfl_xor(s, wd);
        float nm = fmaxf(m, mo);
        float e0 = __expf(m - nm), e1 = __expf(mo - nm);
        s = s * e0 + so * e1;
#pragma unroll
        for (int i = 0; i < 16; i++) {
            float ao = __shfl_xor(acc[i], wd);
            acc[i] = acc[i] * e0 + ao * e1;
        }
        m = nm;
    }
    float inv = 1.f / (s + 1e-16f);
#pragma unroll
    for (int i = 0; i < 16; i++) o[i] += acc[i] * inv;
}

template <int LANES>
__device__ __forceinline__ void job_run(const AggrArgs& a, int wid, int nd, int rel, int roff,
                                        size_t xoff, int rel2, int roff2) {
    const int lane = wid % LANES;
    const int grp = wid / LANES;
    const int d = grp >> 2, h = grp & 3;
    if (d >= nd) return;
    const ush* qp = a.Q + xoff + (size_t)d * 64 + h * 16;
    short8 q0 = *(const short8*)(const void*)qp;
    short8 q1 = *(const short8*)(const void*)(qp + 8);
    float qf[16];
#pragma unroll
    for (int i = 0; i < 8; i++) { qf[i] = b2f((ush)q0[i]); qf[8 + i] = b2f((ush)q1[i]); }
    float o[16];
#pragma unroll
    for (int i = 0; i < 16; i++) o[i] = 0.f;
    seg_attn<LANES>(a, rel, roff + d, h, lane, qf, o);
    if (rel2 >= 0) seg_attn<LANES>(a, rel2, roff2 + d, h, lane, qf, o);
    if (lane == 0) {
        ush* op = a.OUT + xoff + (size_t)d * 64 + h * 16;
        short8 w0, w1;
#pragma unroll
        for (int i = 0; i < 8; i++) {
            float va = o[i];
            w0[i] = (short)f2b(0.5f * va * (1.0f + erff(va * 0.70710678118654752f)));
            float vb = o[8 + i];
            w1[i] = (short)f2b(0.5f * vb * (1.0f + erff(vb * 0.70710678118654752f)));
        }
        *(short8*)(op) = w0;
        *(short8*)(op + 8) = w1;
    }
}

// blocks: [0,250) drugs L=16 | [250,563) diseases L=4 | [563,3688) patients L=2
__global__ __launch_bounds__(256) void aggr_kernel(AggrArgs a) {
    const int b = blockIdx.x, t = threadIdx.x;
    if (b < 250) {
        job_run<16>(a, b * 256 + t, N_D, 0, 0, (size_t)N_P * 64, -1, 0);
    } else if (b < 563) {
        job_run<4>(a, (b - 250) * 256 + t, N_S, 2, 101000, (size_t)(N_P + N_D) * 64, 3, 106000);
    } else {
        job_run<2>(a, (b - 563) * 256 + t, N_P, 1, 1000, 0, -1, 0);
    }
}

// ---------------------------------------------------------------------------
// Epi0 (layer 0, fused with layer-1 Q/KV panels). Dyn LDS 17408 B.
// x = s*(OUT @ Wa + ba) + (1-s)*x computed tile-wise in LDS, stored, then
// the new-X tile feeds gemm_panels for layer-1 Q/KV.
// ---------------------------------------------------------------------------
struct Epi0Args {
    const ush* O;
    ush* X;
    const ush* Wa[3];  // layer-0 epilogue weights (TWA, fragment)
    const ush* Ba[3];
    const ush* skipv;  // layer-0 skip
    const ush* Wq[3];  // layer-1 Q weights (TW, fragment)
    const ush* Bq[3];
    const ush* We[4];  // layer-1 eff weights (weff, fragment)
    ush* Q;
    ush* KVk[4];
    ush* KVv[4];
};

__global__ __launch_bounds__(256) void epi0_kernel(Epi0Args a) {
    extern __shared__ short smem[];
    short* sA = smem;
    short* sB = smem + 64 * 72;
    const int b = blockIdx.x;
    int t, lb, M;
    size_t noff;
    if (b < 1563) { t = 0; lb = b; M = N_P; noff = 0; }
    else if (b < 1579) { t = 1; lb = b - 1563; M = N_D; noff = (size_t)N_P; }
    else { t = 2; lb = b - 1579; M = N_S; noff = (size_t)(N_P + N_D); }
    const ush* O = a.O + noff * 64;
    ush* X = a.X + noff * 64;
    const int tid = threadIdx.x;
    const int w = tid >> 6, l = tid & 63;
    const int row0 = lb * 64;
    // stage gelu-OUT tile (already gelu'd bf16) and Wa fragments
    for (int u = tid; u < 512; u += 256) {
        int r = u >> 3, c0 = (u & 7) * 8;
        int row = row0 + r;
        short8 sv = {0, 0, 0, 0, 0, 0, 0, 0};
        if (row < M) sv = *(const short8*)(const void*)(O + (size_t)row * 64 + c0);
        *(short8*)(&sA[r * 72 + c0]) = sv;
    }
    for (int u = tid; u < 512; u += 256)
        *(short8*)(&sB[u * 8]) = *(const short8*)(const void*)(a.Wa[t] + (size_t)u * 8);
    __syncthreads();
    floatx4 acc[4];
#pragma unroll
    for (int c = 0; c < 4; c++) {
        float bv = b2f(a.Ba[t][16 * c + (l & 15)]);
        acc[c] = (floatx4){bv, bv, bv, bv};
    }
    mfma64_acc(sA, sB, acc);
    __syncthreads();
    // old X tile -> sA (coalesced)
    for (int u = tid; u < 512; u += 256) {
        int r = u >> 3, c0 = (u & 7) * 8;
        int row = row0 + r;
        if (row < M)
            *(short8*)(&sA[r * 72 + c0]) =
                *(const short8*)(const void*)(X + (size_t)row * 64 + c0);
    }
    __syncthreads();
    const float sg = 1.f / (1.f + expf(-b2f(a.skipv[t])));
    // blend in place (each thread owns its 16 cells)
#pragma unroll
    for (int c = 0; c < 4; c++)
#pragma unroll
        for (int r = 0; r < 4; r++) {
            int rr = 16 * w + ((l >> 4) << 2) + r;
            int cc = 16 * c + (l & 15);
            float val = sg * acc[c][r] + (1.f - sg) * b2f((ush)sA[rr * 72 + cc]);
            sA[rr * 72 + cc] = (short)f2b(val);
        }
    __syncthreads();
    // store new X
    for (int u = tid; u < 512; u += 256) {
        int r = u >> 3, c0 = (u & 7) * 8;
        int row = row0 + r;
        if (row < M)
            *(short8*)(X + (size_t)row * 64 + c0) = *(const short8*)(&sA[r * 72 + c0]);
    }
    // layer-1 Q/KV panels from the new-X tile in sA
    run_panels(t, sA, sB, a.Wq, a.Bq, a.We, a.Q, a.KVk, a.KVv, M, row0);
}

// ---------------------------------------------------------------------------
// Final epilogue (layer 1): x_out = s*(OUT @ Wa + ba) + (1-s)*x, fp32/bf16 out.
// ---------------------------------------------------------------------------
struct EpiArgs {
    const ush* O;
    ush* X;
    const ush* W[3];
    const ush* Bb[3];
    const ush* skipv;
    void* fout;
    int foutf;  // 1 = final output fp32, 0 = bf16
    int last;
};

__global__ __launch_bounds__(256) void epi_kernel(EpiArgs a) {
    const int b = blockIdx.x;
    int t, lb, M;
    size_t noff;
    if (b < 1563) { t = 0; lb = b; M = N_P; noff = 0; }
    else if (b < 1579) { t = 1; lb = b - 1563; M = N_D; noff = (size_t)N_P; }
    else { t = 2; lb = b - 1579; M = N_S; noff = (size_t)(N_P + N_D); }
    const ush* O = a.O + noff * 64;
    ush* X = a.X + noff * 64;
    const ush* WF = a.W[t];
    __shared__ short sA[64 * 72];  // reused as fp32 stage (32 x 68 floats)
    __shared__ short sB[8 * 512];
    const int tid = threadIdx.x;
    const int row0 = lb * 64;
    for (int cid = tid; cid < 512; cid += 256) {
        int r = cid >> 3, c0 = (cid & 7) * 8;
        int row = row0 + r;
        short8 sv = {0, 0, 0, 0, 0, 0, 0, 0};
        if (row < M) sv = *(const short8*)(const void*)(O + (size_t)row * 64 + c0);
        *(short8*)(&sA[r * 72 + c0]) = sv;
    }
    for (int u = tid; u < 512; u += 256)
        *(short8*)(&sB[u * 8]) = *(const short8*)(const void*)(WF + (size_t)u * 8);
    __syncthreads();
    const float sg = 1.f / (1.f + expf(-b2f(a.skipv[t])));
    const int w = tid >> 6, l = tid & 63;
    floatx4 acc[4];
#pragma unroll
    for (int c = 0; c < 4; c++) {
        float bv = b2f(a.Bb[t][16 * c + (l & 15)]);
        acc[c] = (floatx4){bv, bv, bv, bv};
    }
#pragma unroll
    for (int s = 0; s < 2; s++) {
        short8 av = *(const short8*)(&sA[(16 * w + (l & 15)) * 72 + 32 * s + ((l >> 4) << 3)]);
#pragma unroll
        for (int c = 0; c < 4; c++) {
            short8 bv = *(const short8*)(&sB[(s * 4 + c) * 512 + l * 8]);
            acc[c] = __builtin_amdgcn_mfma_f32_16x16x32_bf16(av, bv, acc[c], 0, 0, 0);
        }
    }
    float* sOf = (float*)sA;
#pragma unroll
    for (int ch = 0; ch < 2; ch++) {
        __syncthreads();
        if ((w >> 1) == ch) {
#pragma unroll
            for (int c = 0; c < 4; c++)
#pragma unroll
                for (int r = 0; r < 4; r++)
                    sOf[(16 * (w & 1) + ((l >> 4) << 2) + r) * 68 + 16 * c + (l & 15)] =
                        acc[c][r];
        }
        __syncthreads();
        {
            int r = tid >> 3, c0 = (tid & 7) * 8;
            int row = row0 + ch * 32 + r;
            if (row < M) {
                floatx4 f0 = *(const floatx4*)(&sOf[r * 68 + c0]);
                floatx4 f1 = *(const floatx4*)(&sOf[r * 68 + c0 + 4]);
                short8 xv = *(const short8*)(const void*)(X + (size_t)row * 64 + c0);
                float vo[8];
#pragma unroll
                for (int j = 0; j < 4; j++) vo[j] = sg * f0[j] + (1.f - sg) * b2f((ush)xv[j]);
#pragma unroll
                for (int j = 0; j < 4; j++)
                    vo[4 + j] = sg * f1[j] + (1.f - sg) * b2f((ush)xv[4 + j]);
                if (!a.last) {
                    short8 ov;
#pragma unroll
                    for (int j = 0; j < 8; j++) ov[j] = (short)f2b(vo[j]);
                    *(short8*)(X + (size_t)row * 64 + c0) = ov;
                } else {
                    size_t goff = (noff + row) * 64 + c0;
                    if (a.foutf) {
                        floatx4 o0, o1;
#pragma unroll
                        for (int j = 0; j < 4; j++) { o0[j] = vo[j]; o1[j] = vo[4 + j]; }
                        *(floatx4*)((float*)a.fout + goff) = o0;
                        *(floatx4*)((float*)a.fout + goff + 4) = o1;
                    } else {
                        short8 ov;
#pragma unroll
                        for (int j = 0; j < 8; j++) ov[j] = (short)f2b(vo[j]);
                        *(short8*)((ush*)a.fout + goff) = ov;
                    }
                }
            }
        }
    }
}

// ---------------------------------------------------------------------------
extern "C" void kernel_launch(void* const* d_in, const int* in_sizes, int n_in,
                              void* d_out, int out_size, void* d_ws, size_t ws_size,
                              hipStream_t stream) {
    // ---- Workspace layout ----
    char* w = (char*)d_ws;
    w += 64;
    ush* CW = (ush*)w;      w += ((CW_TOTAL * 2 + 63) / 64) * 64;
    ush* WEFFB = (ush*)w;   w += ((size_t)8 * 8320 * 2 + 63) / 64 * 64;
    ush* TW = (ush*)w;      w += (size_t)TW_TOTAL * 2;
    ush* X = (ush*)w;       w += (size_t)NT * 64 * 2;
    ush* Q = (ush*)w;       w += (size_t)NT * 64 * 2;
    ush* KV0 = (ush*)w;     w += (size_t)N_P * 128 * 2;
    ush* KV1 = (ush*)w;     w += (size_t)N_D * 128 * 2;
    ush* KV2 = (ush*)w;     w += (size_t)N_D * 128 * 2;
    ush* KV3 = (ush*)w;     w += (size_t)N_P * 128 * 2;
    ush* OUT = (ush*)w;     w += (size_t)NT * 64 * 4;  // fp32-size slab: HB/CS overlay below
    int* CNT = (int*)w;     w += (size_t)NC * 4;  // r1 region doubles as fillpos
    int* TMP = (int*)w;     w += (size_t)NC * 4;
    int* PART = (int*)w;    w += 512;
    int* ROWPTR = (int*)w;  w += (size_t)(NC + 1) * 4;
    int* COL = (int*)w;     w += (size_t)E_TOT * 4;
    int* HB = (int*)OUT;           // 768000 ints, dead before aggr
    int* CS = (int*)OUT + 800000;  // 48000 ints, same overlay

    // dtype flags from byte sizes (bytes == 2*elems -> bf16, else fp32)
    static const long sz[18] = {4096, 64, 8192, 64, 4096, 64, 24576, 384, 24576, 384,
                                24576, 384, 24576, 384, 8192, 8192, 32, 6};
    ConvArgs ca;
    long cum = 0;
    for (int t = 0; t < 18; t++) {
        ca.src[t] = d_in[3 + t];
        ca.cum[t] = cum;
        ca.fl[t] = (in_sizes[3 + t] != (int)(sz[t] * 2)) ? 1 : 0;
        cum += sz[t];
    }
    ca.cum[18] = cum;

    CsrB cb;
    cb.ei[0] = (const int*)d_in[21];
    cb.ei[1] = (const int*)d_in[23];
    cb.ei[2] = (const int*)d_in[24];
    cb.ei1 = (const int*)d_in[22];

    // K1: convert | zero CNT r1 | histograms | fragment transposes | eff folding
    k1_kernel<<<NCONVB + NZB + NHIST + NTWB + 8, 256, 0, stream>>>(ca, CW, TW, CNT + 1000,
                                                                   cb, HB, WEFFB);

    ush* KVr[4] = {KV0, KV1, KV2, KV3};
    const size_t nsr[4] = {(size_t)N_P, (size_t)N_D, (size_t)N_D, (size_t)N_P};
    const int foutf = (out_size != NT * 64 * 2) ? 1 : 0;

    // K2F: inproj + layer-0 Q/KV panels | chunk-scan | r1 degree counts
    K2FArgs k2;
    k2.raw[0] = d_in[0]; k2.f[0] = (in_sizes[0] != N_P * 64 * 2) ? 1 : 0;
    k2.raw[1] = d_in[1]; k2.f[1] = (in_sizes[1] != N_D * 128 * 2) ? 1 : 0;
    k2.raw[2] = d_in[2]; k2.f[2] = (in_sizes[2] != N_S * 64 * 2) ? 1 : 0;
    k2.Wi[0] = TW + TWINP; k2.Bi[0] = CW + OFF_BINP;
    k2.Wi[1] = TW + TWIND; k2.Bi[1] = CW + OFF_BIND;
    k2.Wi[2] = TW + TWINS; k2.Bi[2] = CW + OFF_BINS;
    k2.X = X;
    for (int t = 0; t < 3; t++) {
        k2.Wq[t] = TW + TWQO + (size_t)(0 * 3 + t) * 4096;
        k2.Bq[t] = CW + OFF_BQ + (0 * 3 + t) * 64;
    }
    for (int r = 0; r < 4; r++) {
        k2.We[r] = WEFFB + (size_t)(0 * 4 + r) * 8320;
        k2.KVk[r] = KVr[r];
        k2.KVv[r] = KVr[r] + nsr[r] * 64;
    }
    k2.Q = Q;
    k2.HB = HB; k2.CS = CS; k2.cnt = CNT; k2.ei1 = cb.ei1;
    k2f_kernel<<<1701 + NBLK_R1, 256, 17408, stream>>>(k2);

    // K3: scanA
    k3_kernel<<<109, 256, 0, stream>>>(CNT, TMP, PART);

    // K4: rowptr | fixHB | zero fillpos
    k4_kernel<<<NSCB + 188 + NZB, 256, 0, stream>>>(TMP, PART, ROWPTR, HB, CS, CNT + 1000);

    // fill: CSR column fill
    FillArgs fa;
    fa.cb = cb;
    fa.HB = HB;
    fa.rowptr = ROWPTR;
    fa.fillpos = CNT;  // kernel indexes fillpos[1000+dst] -> CNT[1000..101000)
    fa.col = COL;
    fill_kernel<<<NHIST + NBLK_R1, 256, 20000, stream>>>(fa);

    // layer 0 aggregation
    AggrArgs aa;
    aa.rowptr = ROWPTR;
    aa.col = COL;
    for (int r = 0; r < 4; r++) {
        aa.KVk[r] = KVr[r];
        aa.KVv[r] = KVr[r] + nsr[r] * 64;
    }
    aa.Q = Q;
    aa.prel = CW + OFF_PREL + 0 * 16;
    aa.OUT = OUT;
    aggr_kernel<<<3688, 256, 0, stream>>>(aa);

    // layer-0 epilogue fused with layer-1 Q/KV panels
    Epi0Args e0;
    e0.O = OUT;
    e0.X = X;
    for (int t = 0; t < 3; t++) {
        e0.Wa[t] = TW + TWAO + (size_t)(0 * 3 + t) * 4096;
        e0.Ba[t] = CW + OFF_BA + (0 * 3 + t) * 64;
        e0.Wq[t] = TW + TWQO + (size_t)(1 * 3 + t) * 4096;
        e0.Bq[t] = CW + OFF_BQ + (1 * 3 + t) * 64;
    }
    e0.skipv = CW + OFF_SKIP + 0 * 3;
    for (int r = 0; r < 4; r++) {
        e0.We[r] = WEFFB + (size_t)(1 * 4 + r) * 8320;
        e0.KVk[r] = KVr[r];
        e0.KVv[r] = KVr[r] + nsr[r] * 64;
    }
    e0.Q = Q;
    epi0_kernel<<<1658, 256, 17408, stream>>>(e0);

    // layer 1 aggregation
    aa.prel = CW + OFF_PREL + 1 * 16;
    aggr_kernel<<<3688, 256, 0, stream>>>(aa);

    // final epilogue (layer 1)
    EpiArgs ea;
    ea.O = OUT;
    ea.X = X;
    for (int t = 0; t < 3; t++) {
        ea.W[t] = TW + TWAO + (size_t)(1 * 3 + t) * 4096;
        ea.Bb[t] = CW + OFF_BA + (1 * 3 + t) * 64;
    }
    ea.skipv = CW + OFF_SKIP + 1 * 3;
    ea.fout = d_out;
    ea.foutf = foutf;
    ea.last = 1;
    epi_kernel<<<1658, 256, 0, stream>>>(ea);
}

// Round 10
// 354.235 us; speedup vs baseline: 1.2066x; 1.2066x over previous
//
#include <hip/hip_runtime.h>
#include <cmath>

typedef unsigned short ush;  // bf16 raw bits
typedef __attribute__((ext_vector_type(8))) short short8;
typedef __attribute__((ext_vector_type(4))) float floatx4;

static constexpr int N_P = 100000, N_D = 1000, N_S = 5000, NT = N_P + N_D + N_S;
static constexpr int NC = 111000;  // concatenated dst slots: r0:1000 | r1:100000 | r2:5000 | r3:5000
static constexpr int E_TOT = 800000;

// hist-CSR geometry
static constexpr int NB0 = 128, NB2 = 64, NB3 = 64;
static constexpr int CH0 = (300000 + NB0 - 1) / NB0;  // 2344
static constexpr int CH2 = (100000 + NB2 - 1) / NB2;  // 1563
static constexpr int HB0_OFF = 0;
static constexpr int HB2_OFF = NB0 * 1000;            // 128000
static constexpr int HB3_OFF = HB2_OFF + NB2 * 5000;  // 448000 -> total 768000
static constexpr int NCH0 = NB0 / 16, NCH2 = NB2 / 16;  // 8, 4
static constexpr int CS0_OFF = 0;
static constexpr int CS2_OFF = NCH0 * 1000;            // 8000
static constexpr int CS3_OFF = CS2_OFF + NCH2 * 5000;  // 28000 -> total 48000
static constexpr int NHIST = NB0 + NB2 + NB3;          // 256
static constexpr int NBLK_R1 = (300000 + 255) / 256;   // 1172
static constexpr int NZB = (100000 + 255) / 256;       // 391

__device__ __forceinline__ float b2f(ush b) { return __uint_as_float(((unsigned)b) << 16); }
__device__ __forceinline__ ush f2b(float f) {
    unsigned u = __float_as_uint(f);
    return (ush)((u + 0x7FFFu + ((u >> 16) & 1u)) >> 16);
}
// load element i of a raw tensor, rounded to bf16 exactly as the CW convert does
__device__ __forceinline__ float ldr(const void* p, int fl, long i) {
    return fl ? b2f(f2b(((const float*)p)[i])) : b2f(((const ush*)p)[i]);
}

// canonical weight-block offsets (bf16 elements), d_in[3..20]
static constexpr size_t OFF_WINP = 0;
static constexpr size_t OFF_BINP = 4096;
static constexpr size_t OFF_WIND = 4160;
static constexpr size_t OFF_BIND = 12352;
static constexpr size_t OFF_WINS = 12416;
static constexpr size_t OFF_BINS = 16512;
static constexpr size_t OFF_WK = 16576;
static constexpr size_t OFF_BK = 41152;
static constexpr size_t OFF_WQ = 41536;
static constexpr size_t OFF_BQ = 66112;
static constexpr size_t OFF_WV = 66496;
static constexpr size_t OFF_BV = 91072;
static constexpr size_t OFF_WA = 91456;
static constexpr size_t OFF_BA = 116032;
static constexpr size_t OFF_AREL = 116416;
static constexpr size_t OFF_MREL = 124608;
static constexpr size_t OFF_PREL = 132800;
static constexpr size_t OFF_SKIP = 132832;
static constexpr size_t CW_TOTAL = 132838;
static constexpr int NCONVB = (int)((CW_TOTAL + 255) / 256);  // 519
static constexpr int NSCB = (NC + 1 + 255) / 256;             // 434

// fragment-layout weight buffer (ush elements)
static constexpr size_t TWINP = 0;      // 4096  (64x64)
static constexpr size_t TWIND = 4096;   // 8192  (128x64)
static constexpr size_t TWINS = 12288;  // 4096
static constexpr size_t TWQO = 16384;   // 6*4096 (l*3+t)
static constexpr size_t TWAO = 40960;   // 6*4096
static constexpr size_t TW_TOTAL = 65536;
static constexpr int NTWB = (int)(TW_TOTAL / 256);  // 256
static constexpr int NEFFB = (8 * 8320 + 255) / 256;  // 260

struct ConvArgs {
    const void* src[18];
    long cum[19];
    int fl[18];  // 1 = fp32 source, 0 = bf16 source (host-derived from in_sizes)
};

struct CsrB {
    const int* ei[3];  // r0, r2, r3 edge arrays
    const int* ei1;    // r1
};

__device__ __forceinline__ void hist_geom(int b, const CsrB& c, int& r, const int*& ei, int& E,
                                          int& ndst, int& e0, int& e1, int& hb) {
    if (b < NB0) {
        r = 0; ei = c.ei[0]; E = 300000; ndst = 1000;
        e0 = b * CH0; hb = HB0_OFF + b * 1000;
    } else if (b < NB0 + NB2) {
        r = 1; ei = c.ei[1]; E = 100000; ndst = 5000;
        e0 = (b - NB0) * CH2; hb = HB2_OFF + (b - NB0) * 5000;
    } else {
        r = 2; ei = c.ei[2]; E = 100000; ndst = 5000;
        e0 = (b - NB0 - NB2) * CH2; hb = HB3_OFF + (b - NB0 - NB2) * 5000;
    }
    e1 = min(E, e0 + ((r == 0) ? CH0 : CH2));
}

__device__ __forceinline__ bool cs_geom(int g, int& idx0, int& step) {
    if (g >= 48000) return false;
    if (g < 8000) {
        int c = g / 1000, d = g % 1000;
        idx0 = HB0_OFF + c * 16 * 1000 + d; step = 1000;
    } else if (g < 28000) {
        int gg = g - 8000, c = gg / 5000, d = gg % 5000;
        idx0 = HB2_OFF + c * 16 * 5000 + d; step = 5000;
    } else {
        int gg = g - 28000, c = gg / 5000, d = gg % 5000;
        idx0 = HB3_OFF + c * 16 * 5000 + d; step = 5000;
    }
    return true;
}

// ---------------------------------------------------------------------------
// K1: convert weights | zero CNT r1 | histograms | fragment transposes |
//     eff K|V folding (element-parallel: 260 blocks, 1 elem/thread).
// ---------------------------------------------------------------------------
__global__ __launch_bounds__(256) void k1_kernel(ConvArgs a, ush* __restrict__ dst,
                                                 ush* __restrict__ tw,
                                                 int* __restrict__ cnt_r1, CsrB c,
                                                 int* __restrict__ HB,
                                                 ush* __restrict__ weff) {
    const int b = blockIdx.x;
    if (b < NCONVB) {
        long g = (long)b * 256 + threadIdx.x;
        if (g >= (long)CW_TOTAL) return;
        int t = 0;
        while (g >= a.cum[t + 1]) t++;
        long i = g - a.cum[t];
        float v = a.fl[t] ? ((const float*)a.src[t])[i] : b2f(((const ush*)a.src[t])[i]);
        dst[g] = f2b(v);
    } else if (b < NCONVB + NZB) {
        int g = (b - NCONVB) * 256 + threadIdx.x;
        if (g < 100000) cnt_r1[g] = 0;
    } else if (b < NCONVB + NZB + NHIST) {
        __shared__ int h[5000];
        int r, E, ndst, e0, e1, hb;
        const int* ei;
        hist_geom(b - NCONVB - NZB, c, r, ei, E, ndst, e0, e1, hb);
        for (int d = threadIdx.x; d < ndst; d += 256) h[d] = 0;
        __syncthreads();
        for (int e = e0 + threadIdx.x; e < e1; e += 256) atomicAdd(&h[ei[E + e]], 1);
        __syncthreads();
        for (int d = threadIdx.x; d < ndst; d += 256) HB[hb + d] = h[d];
    } else if (b < NCONVB + NZB + NHIST + NTWB) {
        int g = (b - NCONVB - NZB - NHIST) * 256 + threadIdx.x;  // [0, 65536)
        const void* src; int fl; long ibase; int e;
        if (g < 4096) { src = a.src[0]; fl = a.fl[0]; e = g; ibase = 0; }
        else if (g < 12288) { src = a.src[2]; fl = a.fl[2]; e = g - 4096; ibase = 0; }
        else if (g < 16384) { src = a.src[4]; fl = a.fl[4]; e = g - 12288; ibase = 0; }
        else if (g < 40960) { int ee = g - 16384; src = a.src[8]; fl = a.fl[8];
                              e = ee & 4095; ibase = (long)(ee >> 12) * 4096; }
        else { int ee = g - 40960; src = a.src[12]; fl = a.fl[12];
               e = ee & 4095; ibase = (long)(ee >> 12) * 4096; }
        int f = e >> 9, l = (e >> 3) & 63, j = e & 7;
        int s = f >> 2, cc = f & 3;
        long in = ibase + (long)(32 * s + ((l >> 4) << 3) + j) * 64 + 16 * cc + (l & 15);
        float v = fl ? ((const float*)src)[in] : b2f(((const ush*)src)[in]);
        tw[g] = f2b(v);
    } else {
        // eff folding: 8*8320 elements, one per thread (no serial tail)
        int g = (b - NCONVB - NZB - NHIST - NTWB) * 256 + threadIdx.x;
        if (g >= 8 * 8320) return;
        const int eb = g / 8320;  // l*4+r
        const int idx = g % 8320;
        const int l = eb >> 2, r = eb & 3;
        const int st_of[4] = {0, 1, 1, 0};
        const int st = st_of[r];
        int k, n;
        if (idx < 8192) {
            int f = idx >> 9, ll = (idx >> 3) & 63, j = idx & 7;
            int s = f >> 3, cc = f & 7;
            k = 32 * s + ((ll >> 4) << 3) + j;
            n = 16 * cc + (ll & 15);
        } else { k = -1; n = idx - 8192; }
        int kv = n >= 64;
        int jj = n & 63, h = jj >> 4, e = jj & 15;
        const void* Wp = kv ? a.src[10] : a.src[6];
        const int flW = kv ? a.fl[10] : a.fl[6];
        const void* Bp = kv ? a.src[11] : a.src[7];
        const int flB = kv ? a.fl[11] : a.fl[7];
        const void* Rp = kv ? a.src[15] : a.src[14];
        const int flR = kv ? a.fl[15] : a.fl[14];
        const long wb = (long)(l * 3 + st) * 4096;
        const long bb = (long)(l * 3 + st) * 64;
        const long rb = (long)(l * 4 + r) * 1024;
        float acc = 0.f;
        if (k >= 0) {
#pragma unroll
            for (int d = 0; d < 16; d++)
                acc += ldr(Wp, flW, wb + k * 64 + h * 16 + d) *
                       ldr(Rp, flR, rb + h * 256 + d * 16 + e);
        } else {
#pragma unroll
            for (int d = 0; d < 16; d++)
                acc += ldr(Bp, flB, bb + h * 16 + d) *
                       ldr(Rp, flR, rb + h * 256 + d * 16 + e);
        }
        weff[(size_t)eb * 8320 + idx] = f2b(acc);
    }
}

// ---------------------------------------------------------------------------
// MFMA building blocks.
// ---------------------------------------------------------------------------
template <int K>
__device__ __forceinline__ void stage_A_raw(short* sA, const void* __restrict__ X, int f,
                                            int M, int row0) {
    for (int cid = threadIdx.x; cid < 64 * K / 8; cid += 256) {
        int r = cid / (K / 8), c0 = (cid % (K / 8)) * 8;
        int row = row0 + r;
        short8 v = {0, 0, 0, 0, 0, 0, 0, 0};
        if (row < M) {
            if (f) {
                const floatx4* fp = (const floatx4*)((const float*)X + (size_t)row * K + c0);
                floatx4 f0 = fp[0], f1 = fp[1];
#pragma unroll
                for (int j = 0; j < 4; j++) v[j] = (short)f2b(f0[j]);
#pragma unroll
                for (int j = 0; j < 4; j++) v[4 + j] = (short)f2b(f1[j]);
            } else {
                v = *(const short8*)(const void*)((const ush*)X + (size_t)row * K + c0);
            }
        }
        *(short8*)(&sA[r * (K + 8) + c0]) = v;
    }
}

// stage a 64-col half of a [M][128] raw tensor into sA (stride 72)
__device__ __forceinline__ void stage_A_half(short* sA, const void* __restrict__ X, int f,
                                             int M, int row0, int half) {
    for (int cid = threadIdx.x; cid < 512; cid += 256) {
        int r = cid >> 3, c0 = (cid & 7) * 8;
        int row = row0 + r;
        short8 v = {0, 0, 0, 0, 0, 0, 0, 0};
        if (row < M) {
            long off = (long)row * 128 + half * 64 + c0;
            if (f) {
                const floatx4* fp = (const floatx4*)((const float*)X + off);
                floatx4 f0 = fp[0], f1 = fp[1];
#pragma unroll
                for (int j = 0; j < 4; j++) v[j] = (short)f2b(f0[j]);
#pragma unroll
                for (int j = 0; j < 4; j++) v[4 + j] = (short)f2b(f1[j]);
            } else {
                v = *(const short8*)(const void*)((const ush*)X + off);
            }
        }
        *(short8*)(&sA[r * 72 + c0]) = v;
    }
}

// one K=64 MFMA pass: A from sA (stride 72), B frags from sB, accumulate.
__device__ __forceinline__ void mfma64_acc(const short* sA, const short* sB, floatx4* acc) {
    const int tid = threadIdx.x;
    const int w = tid >> 6, l = tid & 63;
#pragma unroll
    for (int s = 0; s < 2; s++) {
        short8 av = *(const short8*)(&sA[(16 * w + (l & 15)) * 72 + 32 * s + ((l >> 4) << 3)]);
#pragma unroll
        for (int c = 0; c < 4; c++) {
            short8 bv = *(const short8*)(&sB[(s * 4 + c) * 512 + l * 8]);
            acc[c] = __builtin_amdgcn_mfma_f32_16x16x32_bf16(av, bv, acc[c], 0, 0, 0);
        }
    }
}

// ---------------------------------------------------------------------------
// 5-panel streaming QKV gemm: A-fragments in registers (sA freed -> output
// stage), per panel {stage 8KB B, 8 MFMAs, scatter, coalesced store}.
// Panels: 0=Q, 1=relA.K, 2=relA.V, 3=relB.K, 4=relB.V (all ld-64).
// ---------------------------------------------------------------------------
template <int NP>
__device__ __forceinline__ void gemm_panels(short* sA, short* sB,
                                            const ush* __restrict__ Wq,
                                            const ush* __restrict__ Bq, ush* __restrict__ Yq,
                                            const ush* __restrict__ WeA,
                                            ush* __restrict__ YAk, ush* __restrict__ YAv,
                                            const ush* __restrict__ WeB,
                                            ush* __restrict__ YBk, ush* __restrict__ YBv,
                                            int M, int row0) {
    const int tid = threadIdx.x;
    const int w = tid >> 6, l = tid & 63;
    __syncthreads();  // X-tile in sA visible
    short8 a0 = *(const short8*)(&sA[(16 * w + (l & 15)) * 72 + ((l >> 4) << 3)]);
    short8 a1 = *(const short8*)(&sA[(16 * w + (l & 15)) * 72 + 32 + ((l >> 4) << 3)]);
    ush* dst[5] = {Yq, YAk, YAv, YBk, YBv};
#pragma unroll
    for (int p = 0; p < NP; p++) {
        __syncthreads();  // prev MFMA done with sB; prev store done with sA-out; a-regs loaded
        const ush* base = (p == 0) ? Wq : ((p <= 2) ? WeA : WeB);
        const int nw = (p == 0) ? 4 : 8;
        const int moff = (p == 0 || p == 1 || p == 3) ? 0 : 4;
        for (int u = tid; u < 512; u += 256) {
            int f = u >> 6, k = u & 63;  // f = s*4 + c
            int s = f >> 2, c = f & 3;
            const ush* src = base + (size_t)(s * nw + moff + c) * 512;
            *(short8*)(&sB[f * 512 + k * 8]) = *(const short8*)(const void*)(src + k * 8);
        }
        __syncthreads();
        const ush* bias = (p == 0) ? Bq : ((p <= 2) ? WeA + 8192 : WeB + 8192);
        const int boff = (p == 0 || p == 1 || p == 3) ? 0 : 64;
        floatx4 acc[4];
#pragma unroll
        for (int c = 0; c < 4; c++) {
            float bv = b2f(bias[boff + 16 * c + (l & 15)]);
            acc[c] = (floatx4){bv, bv, bv, bv};
        }
#pragma unroll
        for (int c = 0; c < 4; c++) {
            short8 b0 = *(const short8*)(&sB[c * 512 + l * 8]);
            acc[c] = __builtin_amdgcn_mfma_f32_16x16x32_bf16(a0, b0, acc[c], 0, 0, 0);
            short8 b1 = *(const short8*)(&sB[(4 + c) * 512 + l * 8]);
            acc[c] = __builtin_amdgcn_mfma_f32_16x16x32_bf16(a1, b1, acc[c], 0, 0, 0);
        }
#pragma unroll
        for (int c = 0; c < 4; c++)
#pragma unroll
            for (int r = 0; r < 4; r++)
                sA[(16 * w + ((l >> 4) << 2) + r) * 72 + 16 * c + (l & 15)] =
                    (short)f2b(acc[c][r]);
        __syncthreads();
        ush* Y = dst[p];
        for (int u = tid; u < 512; u += 256) {
            int r = u >> 3, c0 = (u & 7) * 8;
            int row = row0 + r;
            if (row < M)
                *(short8*)(Y + (size_t)row * 64 + c0) = *(const short8*)(&sA[r * 72 + c0]);
        }
    }
}

__device__ __forceinline__ void run_panels(int t, short* sA, short* sB,
                                           const ush* const* Wq, const ush* const* Bq,
                                           const ush* const* We, ush* Q,
                                           ush* const* KVk, ush* const* KVv,
                                           int M, int row0) {
    if (t == 0)
        gemm_panels<5>(sA, sB, Wq[0], Bq[0], Q, We[0], KVk[0], KVv[0],
                       We[3], KVk[3], KVv[3], M, row0);
    else if (t == 1)
        gemm_panels<5>(sA, sB, Wq[1], Bq[1], Q + (size_t)N_P * 64, We[1], KVk[1], KVv[1],
                       We[2], KVk[2], KVv[2], M, row0);
    else
        gemm_panels<1>(sA, sB, Wq[2], Bq[2], Q + (size_t)(N_P + N_D) * 64,
                       nullptr, nullptr, nullptr, nullptr, nullptr, nullptr, M, row0);
}

// ---------------------------------------------------------------------------
// K2F: fused input projections + layer-0 Q/KV panels | chunk-scan | r1 counts.
// Dyn LDS: sA 9216 + sB 8192 = 17408 B (D's K=128 done as two K=64 halves).
// ---------------------------------------------------------------------------
struct K2FArgs {
    const void* raw[3];
    int f[3];
    const ush* Wi[3];  // inproj fragment weights (TW)
    const ush* Bi[3];  // inproj biases (CW)
    ush* X;
    const ush* Wq[3];  // layer-0 Q fragment weights (TW)
    const ush* Bq[3];
    const ush* We[4];  // layer-0 eff fragment weights (weff)
    ush* Q;
    ush* KVk[4];
    ush* KVv[4];
    const int* HB;
    int* CS;
    int* cnt;
    const int* ei1;
};

__global__ __launch_bounds__(256) void k2f_kernel(K2FArgs a) {
    extern __shared__ short smem[];
    const int b = blockIdx.x;
    if (b < 1658) {
        short* sA = smem;
        short* sB = smem + 64 * 72;
        const int tid = threadIdx.x;
        const int w = tid >> 6, l = tid & 63;
        int t, lb, M;
        if (b < 1563) { t = 0; lb = b; M = N_P; }
        else if (b < 1579) { t = 1; lb = b - 1563; M = N_D; }
        else { t = 2; lb = b - 1579; M = N_S; }
        const size_t noff = (t == 0) ? 0 : (t == 1) ? (size_t)N_P : (size_t)(N_P + N_D);
        const int row0 = lb * 64;
        floatx4 acc[4];
#pragma unroll
        for (int c = 0; c < 4; c++) {
            float bv = b2f(a.Bi[t][16 * c + (l & 15)]);
            acc[c] = (floatx4){bv, bv, bv, bv};
        }
        if (t != 1) {
            stage_A_raw<64>(sA, a.raw[t], a.f[t], M, row0);
            for (int u = tid; u < 512; u += 256)
                *(short8*)(&sB[u * 8]) = *(const short8*)(const void*)(a.Wi[t] + (size_t)u * 8);
            __syncthreads();
            mfma64_acc(sA, sB, acc);
        } else {
#pragma unroll
            for (int hh = 0; hh < 2; hh++) {
                if (hh) __syncthreads();  // prev MFMA reads done before restage
                stage_A_half(sA, a.raw[1], a.f[1], M, row0, hh);
                for (int u = tid; u < 512; u += 256)
                    *(short8*)(&sB[u * 8]) =
                        *(const short8*)(const void*)(a.Wi[1] + (size_t)hh * 4096 + (size_t)u * 8);
                __syncthreads();
                mfma64_acc(sA, sB, acc);
            }
        }
        __syncthreads();
        // scatter X tile into sA (72-stride)
#pragma unroll
        for (int c = 0; c < 4; c++)
#pragma unroll
            for (int r = 0; r < 4; r++)
                sA[(16 * w + ((l >> 4) << 2) + r) * 72 + 16 * c + (l & 15)] =
                    (short)f2b(acc[c][r]);
        __syncthreads();
        ush* Xb = a.X + noff * 64;
        for (int u = tid; u < 512; u += 256) {
            int r = u >> 3, c0 = (u & 7) * 8;
            int row = row0 + r;
            if (row < M)
                *(short8*)(Xb + (size_t)row * 64 + c0) = *(const short8*)(&sA[r * 72 + c0]);
        }
        run_panels(t, sA, sB, a.Wq, a.Bq, a.We, a.Q, a.KVk, a.KVv, M, row0);
    } else if (b < 1701) {
        int d = (b - 1658) * 256 + threadIdx.x;
        if (d >= 11000) return;
        int ld_, nch, base, step, cs0, csstep, roff;
        if (d < 1000) { ld_ = d; nch = NCH0; base = HB0_OFF + ld_; step = 1000;
                        cs0 = CS0_OFF + ld_; csstep = 1000; roff = 0; }
        else if (d < 6000) { ld_ = d - 1000; nch = NCH2; base = HB2_OFF + ld_; step = 5000;
                             cs0 = CS2_OFF + ld_; csstep = 5000; roff = 101000; }
        else { ld_ = d - 6000; nch = NCH2; base = HB3_OFF + ld_; step = 5000;
               cs0 = CS3_OFF + ld_; csstep = 5000; roff = 106000; }
        int run = 0;
        for (int cc = 0; cc < nch; cc++) {
            int s = 0;
#pragma unroll
            for (int bb = 0; bb < 16; bb++) s += a.HB[base + (cc * 16 + bb) * step];
            a.CS[cs0 + cc * csstep] = run;
            run += s;
        }
        a.cnt[roff + ld_] = run;
    } else {
        int g = (b - 1701) * 256 + threadIdx.x;
        if (g < 300000) atomicAdd(&a.cnt[1000 + a.ei1[300000 + g]], 1);
    }
}

// ---------------------------------------------------------------------------
// K3: scanA (block-local scan + partials) only.
// ---------------------------------------------------------------------------
__global__ __launch_bounds__(256) void k3_kernel(const int* __restrict__ cnt,
                                                 int* __restrict__ tmp,
                                                 int* __restrict__ part) {
    const int b = blockIdx.x;
    __shared__ int ls[256];
    const int t = threadIdx.x;
    const int base = b * 1024 + t * 4;
    int v[4];
#pragma unroll
    for (int j = 0; j < 4; j++) v[j] = (base + j < NC) ? cnt[base + j] : 0;
    int tsum = v[0] + v[1] + v[2] + v[3];
    ls[t] = tsum;
    __syncthreads();
    for (int off = 1; off < 256; off <<= 1) {
        int y = (t >= off) ? ls[t - off] : 0;
        __syncthreads();
        ls[t] += y;
        __syncthreads();
    }
    int run = ls[t] - tsum;
#pragma unroll
    for (int j = 0; j < 4; j++) {
        if (base + j < NC) tmp[base + j] = run;
        run += v[j];
    }
    if (t == 255) part[b] = ls[255];
}

// ---------------------------------------------------------------------------
// K4: rowptr (inline partial rescan) | fixHB | zero fillpos.
// ---------------------------------------------------------------------------
__global__ __launch_bounds__(256) void k4_kernel(const int* __restrict__ tmp,
                                                 const int* __restrict__ part,
                                                 int* __restrict__ rowptr,
                                                 int* __restrict__ HB,
                                                 const int* __restrict__ CS,
                                                 int* __restrict__ fillpos) {
    const int b = blockIdx.x;
    if (b < NSCB) {
        __shared__ int ls[256];
        const int t = threadIdx.x;
        ls[t] = (t < 109) ? part[t] : 0;
        __syncthreads();
        for (int off = 1; off < 256; off <<= 1) {
            int y = (t >= off) ? ls[t - off] : 0;
            __syncthreads();
            ls[t] += y;
            __syncthreads();
        }
        int i = b * 256 + t;
        if (i <= NC)
            rowptr[i] = (i == NC) ? ls[255] : tmp[i] + ((i >> 10) ? ls[(i >> 10) - 1] : 0);
    } else if (b < NSCB + 188) {
        int g = (b - NSCB) * 256 + threadIdx.x;
        int idx0, step;
        if (!cs_geom(g, idx0, step)) return;
        int run = CS[g];
#pragma unroll
        for (int bb = 0; bb < 16; bb++) {
            int t2 = HB[idx0 + bb * step];
            HB[idx0 + bb * step] = run;
            run += t2;
        }
    } else {
        int g = (b - NSCB - 188) * 256 + threadIdx.x;
        if (g < 100000) fillpos[g] = 0;
    }
}

// ---------------------------------------------------------------------------
// fill: CSR column fill (layer 0 only). Dyn LDS: 20000 B.
// ---------------------------------------------------------------------------
struct FillArgs {
    CsrB cb;
    const int* HB;
    const int* rowptr;
    int* fillpos;  // == CNT base; kernel indexes fillpos[1000 + dst]
    int* col;
};

__global__ __launch_bounds__(256) void fill_kernel(FillArgs a) {
    extern __shared__ short smem[];
    const int b = blockIdx.x;
    if (b < NHIST) {
        int* h = (int*)smem;
        int r, E, ndst, e0, e1, hb;
        const int* ei;
        hist_geom(b, a.cb, r, ei, E, ndst, e0, e1, hb);
        const int roff = (r == 0) ? 0 : (r == 1) ? 101000 : 106000;
        for (int d = threadIdx.x; d < ndst; d += 256) h[d] = a.rowptr[roff + d] + a.HB[hb + d];
        __syncthreads();
        for (int e = e0 + threadIdx.x; e < e1; e += 256) {
            int d = ei[E + e];
            int slot = atomicAdd(&h[d], 1);
            a.col[slot] = ei[e];
        }
    } else {
        int g = (b - NHIST) * 256 + threadIdx.x;
        if (g < 300000) {
            int gi = 1000 + a.cb.ei1[300000 + g];
            int slot = a.rowptr[gi] + atomicAdd(&a.fillpos[gi], 1);
            a.col[slot] = a.cb.ei1[g];
        }
    }
}

// ---------------------------------------------------------------------------
// Fused gather aggregation; K/V in split half-arrays; writes gelu(out) bf16.
// Fixed per-lane shift softmax (peeled first edge) -> independent iterations;
// unroll-2 software pipeline for MLP.
// ---------------------------------------------------------------------------
struct AggrArgs {
    const int* rowptr;
    const int* col;
    const ush* KVk[4];
    const ush* KVv[4];
    const ush* Q;
    const ush* prel;
    ush* OUT;
};

template <int LANES>
__device__ __forceinline__ void seg_attn(const AggrArgs& a, int rel, int g, int h, int lane,
                                         const float* qf, float* o) {
    const int s0 = a.rowptr[g], s1 = a.rowptr[g + 1];
    const ush* Kb = a.KVk[rel];
    const ush* Vb = a.KVv[rel];
    const float ps = b2f(a.prel[rel * 4 + h]) * 0.25f;
    float m = -1e30f, s = 0.f;
    float acc[16];
#pragma unroll
    for (int i = 0; i < 16; i++) acc[i] = 0.f;
    int j = s0 + lane;
    if (j < s1) {
        {
            int src = a.col[j];
            const ush* kp = Kb + (size_t)src * 64 + h * 16;
            const ush* vp = Vb + (size_t)src * 64 + h * 16;
            short8 k0 = *(const short8*)(const void*)kp;
            short8 k1 = *(const short8*)(const void*)(kp + 8);
            short8 v0 = *(const short8*)(const void*)vp;
            short8 v1 = *(const short8*)(const void*)(vp + 8);
            float dot = 0.f;
#pragma unroll
            for (int i = 0; i < 8; i++) dot += qf[i] * b2f((ush)k0[i]);
#pragma unroll
            for (int i = 0; i < 8; i++) dot += qf[8 + i] * b2f((ush)k1[i]);
            m = dot * ps;
            s = 1.f;
#pragma unroll
            for (int i = 0; i < 8; i++) acc[i] = b2f((ush)v0[i]);
#pragma unroll
            for (int i = 0; i < 8; i++) acc[8 + i] = b2f((ush)v1[i]);
        }
        j += LANES;
        for (; j + LANES < s1; j += 2 * LANES) {
            int srcA = a.col[j];
            int srcB = a.col[j + LANES];
            const ush* kpA = Kb + (size_t)srcA * 64 + h * 16;
            const ush* vpA = Vb + (size_t)srcA * 64 + h * 16;
            const ush* kpB = Kb + (size_t)srcB * 64 + h * 16;
            const ush* vpB = Vb + (size_t)srcB * 64 + h * 16;
            short8 k0A = *(const short8*)(const void*)kpA;
            short8 k1A = *(const short8*)(const void*)(kpA + 8);
            short8 v0A = *(const short8*)(const void*)vpA;
            short8 v1A = *(const short8*)(const void*)(vpA + 8);
            short8 k0B = *(const short8*)(const void*)kpB;
            short8 k1B = *(const short8*)(const void*)(kpB + 8);
            short8 v0B = *(const short8*)(const void*)vpB;
            short8 v1B = *(const short8*)(const void*)(vpB + 8);
            float dotA = 0.f, dotB = 0.f;
#pragma unroll
            for (int i = 0; i < 8; i++) dotA += qf[i] * b2f((ush)k0A[i]);
#pragma unroll
            for (int i = 0; i < 8; i++) dotA += qf[8 + i] * b2f((ush)k1A[i]);
#pragma unroll
            for (int i = 0; i < 8; i++) dotB += qf[i] * b2f((ush)k0B[i]);
#pragma unroll
            for (int i = 0; i < 8; i++) dotB += qf[8 + i] * b2f((ush)k1B[i]);
            float eA = __expf(dotA * ps - m);
            float eB = __expf(dotB * ps - m);
            s += eA + eB;
#pragma unroll
            for (int i = 0; i < 8; i++) acc[i] += eA * b2f((ush)v0A[i]) + eB * b2f((ush)v0B[i]);
#pragma unroll
            for (int i = 0; i < 8; i++)
                acc[8 + i] += eA * b2f((ush)v1A[i]) + eB * b2f((ush)v1B[i]);
        }
        if (j < s1) {
            int src = a.col[j];
            const ush* kp = Kb + (size_t)src * 64 + h * 16;
            const ush* vp = Vb + (size_t)src * 64 + h * 16;
            short8 k0 = *(const short8*)(const void*)kp;
            short8 k1 = *(const short8*)(const void*)(kp + 8);
            short8 v0 = *(const short8*)(const void*)vp;
            short8 v1 = *(const short8*)(const void*)(vp + 8);
            float dot = 0.f;
#pragma unroll
            for (int i = 0; i < 8; i++) dot += qf[i] * b2f((ush)k0[i]);
#pragma unroll
            for (int i = 0; i < 8; i++) dot += qf[8 + i] * b2f((ush)k1[i]);
            float e1 = __expf(dot * ps - m);
            s += e1;
#pragma unroll
            for (int i = 0; i < 8; i++) acc[i] += e1 * b2f((ush)v0[i]);
#pragma unroll
            for (int i = 0; i < 8; i++) acc[8 + i] += e1 * b2f((ush)v1[i]);
        }
    }
#pragma unroll
    for (int wd = LANES >> 1; wd >= 1; wd >>= 1) {
        float mo = __shfl_xor(m, wd);
        float so = __shfl_xor(s, wd);
        float nm = fmaxf(m, mo);
        float e0 = __expf(m - nm), e1 = __expf(mo - nm);
        s = s * e0 + so * e1;
#pragma unroll
        for (int i = 0; i < 16; i++) {
            float ao = __shfl_xor(acc[i], wd);
            acc[i] = acc[i] * e0 + ao * e1;
        }
        m = nm;
    }
    float inv = 1.f / (s + 1e-16f);
#pragma unroll
    for (int i = 0; i < 16; i++) o[i] += acc[i] * inv;
}

template <int LANES>
__device__ __forceinline__ void job_run(const AggrArgs& a, int wid, int nd, int rel, int roff,
                                        size_t xoff, int rel2, int roff2) {
    const int lane = wid % LANES;
    const int grp = wid / LANES;
    const int d = grp >> 2, h = grp & 3;
    if (d >= nd) return;
    const ush* qp = a.Q + xoff + (size_t)d * 64 + h * 16;
    short8 q0 = *(const short8*)(const void*)qp;
    short8 q1 = *(const short8*)(const void*)(qp + 8);
    float qf[16];
#pragma unroll
    for (int i = 0; i < 8; i++) { qf[i] = b2f((ush)q0[i]); qf[8 + i] = b2f((ush)q1[i]); }
    float o[16];
#pragma unroll
    for (int i = 0; i < 16; i++) o[i] = 0.f;
    seg_attn<LANES>(a, rel, roff + d, h, lane, qf, o);
    if (rel2 >= 0) seg_attn<LANES>(a, rel2, roff2 + d, h, lane, qf, o);
    if (lane == 0) {
        ush* op = a.OUT + xoff + (size_t)d * 64 + h * 16;
        short8 w0, w1;
#pragma unroll
        for (int i = 0; i < 8; i++) {
            float va = o[i];
            w0[i] = (short)f2b(0.5f * va * (1.0f + erff(va * 0.70710678118654752f)));
            float vb = o[8 + i];
            w1[i] = (short)f2b(0.5f * vb * (1.0f + erff(vb * 0.70710678118654752f)));
        }
        *(short8*)(op) = w0;
        *(short8*)(op + 8) = w1;
    }
}

// blocks: [0,250) drugs L=16 | [250,563) diseases L=4 | [563,3688) patients L=2
__global__ __launch_bounds__(256) void aggr_kernel(AggrArgs a) {
    const int b = blockIdx.x, t = threadIdx.x;
    if (b < 250) {
        job_run<16>(a, b * 256 + t, N_D, 0, 0, (size_t)N_P * 64, -1, 0);
    } else if (b < 563) {
        job_run<4>(a, (b - 250) * 256 + t, N_S, 2, 101000, (size_t)(N_P + N_D) * 64, 3, 106000);
    } else {
        job_run<2>(a, (b - 563) * 256 + t, N_P, 1, 1000, 0, -1, 0);
    }
}

// ---------------------------------------------------------------------------
// Epi0 (layer 0, fused with layer-1 Q/KV panels). Dyn LDS 17408 B.
// ---------------------------------------------------------------------------
struct Epi0Args {
    const ush* O;
    ush* X;
    const ush* Wa[3];  // layer-0 epilogue weights (TWA, fragment)
    const ush* Ba[3];
    const ush* skipv;  // layer-0 skip
    const ush* Wq[3];  // layer-1 Q weights (TW, fragment)
    const ush* Bq[3];
    const ush* We[4];  // layer-1 eff weights (weff, fragment)
    ush* Q;
    ush* KVk[4];
    ush* KVv[4];
};

__global__ __launch_bounds__(256) void epi0_kernel(Epi0Args a) {
    extern __shared__ short smem[];
    short* sA = smem;
    short* sB = smem + 64 * 72;
    const int b = blockIdx.x;
    int t, lb, M;
    size_t noff;
    if (b < 1563) { t = 0; lb = b; M = N_P; noff = 0; }
    else if (b < 1579) { t = 1; lb = b - 1563; M = N_D; noff = (size_t)N_P; }
    else { t = 2; lb = b - 1579; M = N_S; noff = (size_t)(N_P + N_D); }
    const ush* O = a.O + noff * 64;
    ush* X = a.X + noff * 64;
    const int tid = threadIdx.x;
    const int w = tid >> 6, l = tid & 63;
    const int row0 = lb * 64;
    for (int u = tid; u < 512; u += 256) {
        int r = u >> 3, c0 = (u & 7) * 8;
        int row = row0 + r;
        short8 sv = {0, 0, 0, 0, 0, 0, 0, 0};
        if (row < M) sv = *(const short8*)(const void*)(O + (size_t)row * 64 + c0);
        *(short8*)(&sA[r * 72 + c0]) = sv;
    }
    for (int u = tid; u < 512; u += 256)
        *(short8*)(&sB[u * 8]) = *(const short8*)(const void*)(a.Wa[t] + (size_t)u * 8);
    __syncthreads();
    floatx4 acc[4];
#pragma unroll
    for (int c = 0; c < 4; c++) {
        float bv = b2f(a.Ba[t][16 * c + (l & 15)]);
        acc[c] = (floatx4){bv, bv, bv, bv};
    }
    mfma64_acc(sA, sB, acc);
    __syncthreads();
    // old X tile -> sA (coalesced)
    for (int u = tid; u < 512; u += 256) {
        int r = u >> 3, c0 = (u & 7) * 8;
        int row = row0 + r;
        if (row < M)
            *(short8*)(&sA[r * 72 + c0]) =
                *(const short8*)(const void*)(X + (size_t)row * 64 + c0);
    }
    __syncthreads();
    const float sg = 1.f / (1.f + expf(-b2f(a.skipv[t])));
#pragma unroll
    for (int c = 0; c < 4; c++)
#pragma unroll
        for (int r = 0; r < 4; r++) {
            int rr = 16 * w + ((l >> 4) << 2) + r;
            int cc = 16 * c + (l & 15);
            float val = sg * acc[c][r] + (1.f - sg) * b2f((ush)sA[rr * 72 + cc]);
            sA[rr * 72 + cc] = (short)f2b(val);
        }
    __syncthreads();
    for (int u = tid; u < 512; u += 256) {
        int r = u >> 3, c0 = (u & 7) * 8;
        int row = row0 + r;
        if (row < M)
            *(short8*)(X + (size_t)row * 64 + c0) = *(const short8*)(&sA[r * 72 + c0]);
    }
    run_panels(t, sA, sB, a.Wq, a.Bq, a.We, a.Q, a.KVk, a.KVv, M, row0);
}

// ---------------------------------------------------------------------------
// Final epilogue (layer 1): x_out = s*(OUT @ Wa + ba) + (1-s)*x, fp32/bf16 out.
// ---------------------------------------------------------------------------
struct EpiArgs {
    const ush* O;
    ush* X;
    const ush* W[3];
    const ush* Bb[3];
    const ush* skipv;
    void* fout;
    int foutf;  // 1 = final output fp32, 0 = bf16
    int last;
};

__global__ __launch_bounds__(256) void epi_kernel(EpiArgs a) {
    const int b = blockIdx.x;
    int t, lb, M;
    size_t noff;
    if (b < 1563) { t = 0; lb = b; M = N_P; noff = 0; }
    else if (b < 1579) { t = 1; lb = b - 1563; M = N_D; noff = (size_t)N_P; }
    else { t = 2; lb = b - 1579; M = N_S; noff = (size_t)(N_P + N_D); }
    const ush* O = a.O + noff * 64;
    ush* X = a.X + noff * 64;
    const ush* WF = a.W[t];
    __shared__ short sA[64 * 72];  // reused as fp32 stage (32 x 68 floats)
    __shared__ short sB[8 * 512];
    const int tid = threadIdx.x;
    const int row0 = lb * 64;
    for (int cid = tid; cid < 512; cid += 256) {
        int r = cid >> 3, c0 = (cid & 7) * 8;
        int row = row0 + r;
        short8 sv = {0, 0, 0, 0, 0, 0, 0, 0};
        if (row < M) sv = *(const short8*)(const void*)(O + (size_t)row * 64 + c0);
        *(short8*)(&sA[r * 72 + c0]) = sv;
    }
    for (int u = tid; u < 512; u += 256)
        *(short8*)(&sB[u * 8]) = *(const short8*)(const void*)(WF + (size_t)u * 8);
    __syncthreads();
    const float sg = 1.f / (1.f + expf(-b2f(a.skipv[t])));
    const int w = tid >> 6, l = tid & 63;
    floatx4 acc[4];
#pragma unroll
    for (int c = 0; c < 4; c++) {
        float bv = b2f(a.Bb[t][16 * c + (l & 15)]);
        acc[c] = (floatx4){bv, bv, bv, bv};
    }
#pragma unroll
    for (int s = 0; s < 2; s++) {
        short8 av = *(const short8*)(&sA[(16 * w + (l & 15)) * 72 + 32 * s + ((l >> 4) << 3)]);
#pragma unroll
        for (int c = 0; c < 4; c++) {
            short8 bv = *(const short8*)(&sB[(s * 4 + c) * 512 + l * 8]);
            acc[c] = __builtin_amdgcn_mfma_f32_16x16x32_bf16(av, bv, acc[c], 0, 0, 0);
        }
    }
    float* sOf = (float*)sA;
#pragma unroll
    for (int ch = 0; ch < 2; ch++) {
        __syncthreads();
        if ((w >> 1) == ch) {
#pragma unroll
            for (int c = 0; c < 4; c++)
#pragma unroll
                for (int r = 0; r < 4; r++)
                    sOf[(16 * (w & 1) + ((l >> 4) << 2) + r) * 68 + 16 * c + (l & 15)] =
                        acc[c][r];
        }
        __syncthreads();
        {
            int r = tid >> 3, c0 = (tid & 7) * 8;
            int row = row0 + ch * 32 + r;
            if (row < M) {
                floatx4 f0 = *(const floatx4*)(&sOf[r * 68 + c0]);
                floatx4 f1 = *(const floatx4*)(&sOf[r * 68 + c0 + 4]);
                short8 xv = *(const short8*)(const void*)(X + (size_t)row * 64 + c0);
                float vo[8];
#pragma unroll
                for (int j = 0; j < 4; j++) vo[j] = sg * f0[j] + (1.f - sg) * b2f((ush)xv[j]);
#pragma unroll
                for (int j = 0; j < 4; j++)
                    vo[4 + j] = sg * f1[j] + (1.f - sg) * b2f((ush)xv[4 + j]);
                if (!a.last) {
                    short8 ov;
#pragma unroll
                    for (int j = 0; j < 8; j++) ov[j] = (short)f2b(vo[j]);
                    *(short8*)(X + (size_t)row * 64 + c0) = ov;
                } else {
                    size_t goff = (noff + row) * 64 + c0;
                    if (a.foutf) {
                        floatx4 o0, o1;
#pragma unroll
                        for (int j = 0; j < 4; j++) { o0[j] = vo[j]; o1[j] = vo[4 + j]; }
                        *(floatx4*)((float*)a.fout + goff) = o0;
                        *(floatx4*)((float*)a.fout + goff + 4) = o1;
                    } else {
                        short8 ov;
#pragma unroll
                        for (int j = 0; j < 8; j++) ov[j] = (short)f2b(vo[j]);
                        *(short8*)((ush*)a.fout + goff) = ov;
                    }
                }
            }
        }
    }
}

// ---------------------------------------------------------------------------
extern "C" void kernel_launch(void* const* d_in, const int* in_sizes, int n_in,
                              void* d_out, int out_size, void* d_ws, size_t ws_size,
                              hipStream_t stream) {
    // ---- Workspace layout ----
    char* w = (char*)d_ws;
    w += 64;
    ush* CW = (ush*)w;      w += ((CW_TOTAL * 2 + 63) / 64) * 64;
    ush* WEFFB = (ush*)w;   w += ((size_t)8 * 8320 * 2 + 63) / 64 * 64;
    ush* TW = (ush*)w;      w += (size_t)TW_TOTAL * 2;
    ush* X = (ush*)w;       w += (size_t)NT * 64 * 2;
    ush* Q = (ush*)w;       w += (size_t)NT * 64 * 2;
    ush* KV0 = (ush*)w;     w += (size_t)N_P * 128 * 2;
    ush* KV1 = (ush*)w;     w += (size_t)N_D * 128 * 2;
    ush* KV2 = (ush*)w;     w += (size_t)N_D * 128 * 2;
    ush* KV3 = (ush*)w;     w += (size_t)N_P * 128 * 2;
    ush* OUT = (ush*)w;     w += (size_t)NT * 64 * 4;  // fp32-size slab: HB/CS overlay below
    int* CNT = (int*)w;     w += (size_t)NC * 4;  // r1 region doubles as fillpos
    int* TMP = (int*)w;     w += (size_t)NC * 4;
    int* PART = (int*)w;    w += 512;
    int* ROWPTR = (int*)w;  w += (size_t)(NC + 1) * 4;
    int* COL = (int*)w;     w += (size_t)E_TOT * 4;
    int* HB = (int*)OUT;           // 768000 ints, dead before aggr
    int* CS = (int*)OUT + 800000;  // 48000 ints, same overlay

    // dtype flags from byte sizes (bytes == 2*elems -> bf16, else fp32)
    static const long sz[18] = {4096, 64, 8192, 64, 4096, 64, 24576, 384, 24576, 384,
                                24576, 384, 24576, 384, 8192, 8192, 32, 6};
    ConvArgs ca;
    long cum = 0;
    for (int t = 0; t < 18; t++) {
        ca.src[t] = d_in[3 + t];
        ca.cum[t] = cum;
        ca.fl[t] = (in_sizes[3 + t] != (int)(sz[t] * 2)) ? 1 : 0;
        cum += sz[t];
    }
    ca.cum[18] = cum;

    CsrB cb;
    cb.ei[0] = (const int*)d_in[21];
    cb.ei[1] = (const int*)d_in[23];
    cb.ei[2] = (const int*)d_in[24];
    cb.ei1 = (const int*)d_in[22];

    // K1: convert | zero CNT r1 | histograms | fragment transposes | eff folding
    k1_kernel<<<NCONVB + NZB + NHIST + NTWB + NEFFB, 256, 0, stream>>>(ca, CW, TW, CNT + 1000,
                                                                       cb, HB, WEFFB);

    ush* KVr[4] = {KV0, KV1, KV2, KV3};
    const size_t nsr[4] = {(size_t)N_P, (size_t)N_D, (size_t)N_D, (size_t)N_P};
    const int foutf = (out_size != NT * 64 * 2) ? 1 : 0;

    // K2F: inproj + layer-0 Q/KV panels | chunk-scan | r1 degree counts
    K2FArgs k2;
    k2.raw[0] = d_in[0]; k2.f[0] = (in_sizes[0] != N_P * 64 * 2) ? 1 : 0;
    k2.raw[1] = d_in[1]; k2.f[1] = (in_sizes[1] != N_D * 128 * 2) ? 1 : 0;
    k2.raw[2] = d_in[2]; k2.f[2] = (in_sizes[2] != N_S * 64 * 2) ? 1 : 0;
    k2.Wi[0] = TW + TWINP; k2.Bi[0] = CW + OFF_BINP;
    k2.Wi[1] = TW + TWIND; k2.Bi[1] = CW + OFF_BIND;
    k2.Wi[2] = TW + TWINS; k2.Bi[2] = CW + OFF_BINS;
    k2.X = X;
    for (int t = 0; t < 3; t++) {
        k2.Wq[t] = TW + TWQO + (size_t)(0 * 3 + t) * 4096;
        k2.Bq[t] = CW + OFF_BQ + (0 * 3 + t) * 64;
    }
    for (int r = 0; r < 4; r++) {
        k2.We[r] = WEFFB + (size_t)(0 * 4 + r) * 8320;
        k2.KVk[r] = KVr[r];
        k2.KVv[r] = KVr[r] + nsr[r] * 64;
    }
    k2.Q = Q;
    k2.HB = HB; k2.CS = CS; k2.cnt = CNT; k2.ei1 = cb.ei1;
    k2f_kernel<<<1701 + NBLK_R1, 256, 17408, stream>>>(k2);

    // K3: scanA
    k3_kernel<<<109, 256, 0, stream>>>(CNT, TMP, PART);

    // K4: rowptr | fixHB | zero fillpos
    k4_kernel<<<NSCB + 188 + NZB, 256, 0, stream>>>(TMP, PART, ROWPTR, HB, CS, CNT + 1000);

    // fill: CSR column fill
    FillArgs fa;
    fa.cb = cb;
    fa.HB = HB;
    fa.rowptr = ROWPTR;
    fa.fillpos = CNT;  // kernel indexes fillpos[1000+dst] -> CNT[1000..101000)
    fa.col = COL;
    fill_kernel<<<NHIST + NBLK_R1, 256, 20000, stream>>>(fa);

    // layer 0 aggregation
    AggrArgs aa;
    aa.rowptr = ROWPTR;
    aa.col = COL;
    for (int r = 0; r < 4; r++) {
        aa.KVk[r] = KVr[r];
        aa.KVv[r] = KVr[r] + nsr[r] * 64;
    }
    aa.Q = Q;
    aa.prel = CW + OFF_PREL + 0 * 16;
    aa.OUT = OUT;
    aggr_kernel<<<3688, 256, 0, stream>>>(aa);

    // layer-0 epilogue fused with layer-1 Q/KV panels
    Epi0Args e0;
    e0.O = OUT;
    e0.X = X;
    for (int t = 0; t < 3; t++) {
        e0.Wa[t] = TW + TWAO + (size_t)(0 * 3 + t) * 4096;
        e0.Ba[t] = CW + OFF_BA + (0 * 3 + t) * 64;
        e0.Wq[t] = TW + TWQO + (size_t)(1 * 3 + t) * 4096;
        e0.Bq[t] = CW + OFF_BQ + (1 * 3 + t) * 64;
    }
    e0.skipv = CW + OFF_SKIP + 0 * 3;
    for (int r = 0; r < 4; r++) {
        e0.We[r] = WEFFB + (size_t)(1 * 4 + r) * 8320;
        e0.KVk[r] = KVr[r];
        e0.KVv[r] = KVr[r] + nsr[r] * 64;
    }
    e0.Q = Q;
    epi0_kernel<<<1658, 256, 17408, stream>>>(e0);

    // layer 1 aggregation
    aa.prel = CW + OFF_PREL + 1 * 16;
    aggr_kernel<<<3688, 256, 0, stream>>>(aa);

    // final epilogue (layer 1)
    EpiArgs ea;
    ea.O = OUT;
    ea.X = X;
    for (int t = 0; t < 3; t++) {
        ea.W[t] = TW + TWAO + (size_t)(1 * 3 + t) * 4096;
        ea.Bb[t] = CW + OFF_BA + (1 * 3 + t) * 64;
    }
    ea.skipv = CW + OFF_SKIP + 1 * 3;
    ea.fout = d_out;
    ea.foutf = foutf;
    ea.last = 1;
    epi_kernel<<<1658, 256, 0, stream>>>(ea);
}

// Round 11
// 341.780 us; speedup vs baseline: 1.2506x; 1.0364x over previous
//
#include <hip/hip_runtime.h>
#include <cmath>

typedef unsigned short ush;  // bf16 raw bits
typedef __attribute__((ext_vector_type(8))) short short8;
typedef __attribute__((ext_vector_type(4))) float floatx4;

static constexpr int N_P = 100000, N_D = 1000, N_S = 5000, NT = N_P + N_D + N_S;
static constexpr int NC = 111000;  // concatenated dst slots: r0:1000 | r1:100000 | r2:5000 | r3:5000
static constexpr int E_TOT = 800000;

// hist-CSR geometry
static constexpr int NB0 = 128, NB2 = 64, NB3 = 64;
static constexpr int CH0 = (300000 + NB0 - 1) / NB0;  // 2344
static constexpr int CH2 = (100000 + NB2 - 1) / NB2;  // 1563
static constexpr int HB0_OFF = 0;
static constexpr int HB2_OFF = NB0 * 1000;            // 128000
static constexpr int HB3_OFF = HB2_OFF + NB2 * 5000;  // 448000 -> total 768000
static constexpr int NCH0 = NB0 / 16, NCH2 = NB2 / 16;  // 8, 4
static constexpr int CS0_OFF = 0;
static constexpr int CS2_OFF = NCH0 * 1000;            // 8000
static constexpr int CS3_OFF = CS2_OFF + NCH2 * 5000;  // 28000 -> total 48000
static constexpr int NHIST = NB0 + NB2 + NB3;          // 256
static constexpr int NBLK_R1 = (300000 + 255) / 256;   // 1172
static constexpr int NZB = (100000 + 255) / 256;       // 391

__device__ __forceinline__ float b2f(ush b) { return __uint_as_float(((unsigned)b) << 16); }
__device__ __forceinline__ ush f2b(float f) {
    unsigned u = __float_as_uint(f);
    return (ush)((u + 0x7FFFu + ((u >> 16) & 1u)) >> 16);
}
// load element i of a raw tensor, rounded to bf16 exactly as the CW convert does
__device__ __forceinline__ float ldr(const void* p, int fl, long i) {
    return fl ? b2f(f2b(((const float*)p)[i])) : b2f(((const ush*)p)[i]);
}

// canonical weight-block offsets (bf16 elements), d_in[3..20]
static constexpr size_t OFF_WINP = 0;
static constexpr size_t OFF_BINP = 4096;
static constexpr size_t OFF_WIND = 4160;
static constexpr size_t OFF_BIND = 12352;
static constexpr size_t OFF_WINS = 12416;
static constexpr size_t OFF_BINS = 16512;
static constexpr size_t OFF_WK = 16576;
static constexpr size_t OFF_BK = 41152;
static constexpr size_t OFF_WQ = 41536;
static constexpr size_t OFF_BQ = 66112;
static constexpr size_t OFF_WV = 66496;
static constexpr size_t OFF_BV = 91072;
static constexpr size_t OFF_WA = 91456;
static constexpr size_t OFF_BA = 116032;
static constexpr size_t OFF_AREL = 116416;
static constexpr size_t OFF_MREL = 124608;
static constexpr size_t OFF_PREL = 132800;
static constexpr size_t OFF_SKIP = 132832;
static constexpr size_t CW_TOTAL = 132838;
static constexpr int NCONVB = (int)((CW_TOTAL + 255) / 256);  // 519
static constexpr int NSCB = (NC + 1 + 255) / 256;             // 434

// fragment-layout weight buffer (ush elements)
static constexpr size_t TWINP = 0;      // 4096  (64x64)
static constexpr size_t TWIND = 4096;   // 8192  (128x64)
static constexpr size_t TWINS = 12288;  // 4096
static constexpr size_t TWQO = 16384;   // 6*4096 (l*3+t)
static constexpr size_t TWAO = 40960;   // 6*4096
static constexpr size_t TW_TOTAL = 65536;
static constexpr int NTWB = (int)(TW_TOTAL / 256);  // 256
static constexpr int NEFFB = (8 * 8320 + 255) / 256;  // 260

struct ConvArgs {
    const void* src[18];
    long cum[19];
    int fl[18];  // 1 = fp32 source, 0 = bf16 source (host-derived from in_sizes)
};

struct CsrB {
    const int* ei[3];  // r0, r2, r3 edge arrays
    const int* ei1;    // r1
};

__device__ __forceinline__ void hist_geom(int b, const CsrB& c, int& r, const int*& ei, int& E,
                                          int& ndst, int& e0, int& e1, int& hb) {
    if (b < NB0) {
        r = 0; ei = c.ei[0]; E = 300000; ndst = 1000;
        e0 = b * CH0; hb = HB0_OFF + b * 1000;
    } else if (b < NB0 + NB2) {
        r = 1; ei = c.ei[1]; E = 100000; ndst = 5000;
        e0 = (b - NB0) * CH2; hb = HB2_OFF + (b - NB0) * 5000;
    } else {
        r = 2; ei = c.ei[2]; E = 100000; ndst = 5000;
        e0 = (b - NB0 - NB2) * CH2; hb = HB3_OFF + (b - NB0 - NB2) * 5000;
    }
    e1 = min(E, e0 + ((r == 0) ? CH0 : CH2));
}

__device__ __forceinline__ bool cs_geom(int g, int& idx0, int& step) {
    if (g >= 48000) return false;
    if (g < 8000) {
        int c = g / 1000, d = g % 1000;
        idx0 = HB0_OFF + c * 16 * 1000 + d; step = 1000;
    } else if (g < 28000) {
        int gg = g - 8000, c = gg / 5000, d = gg % 5000;
        idx0 = HB2_OFF + c * 16 * 5000 + d; step = 5000;
    } else {
        int gg = g - 28000, c = gg / 5000, d = gg % 5000;
        idx0 = HB3_OFF + c * 16 * 5000 + d; step = 5000;
    }
    return true;
}

// ---------------------------------------------------------------------------
// K1: convert weights | zero CNT r1 | histograms | fragment transposes |
//     eff K|V folding (element-parallel: 260 blocks, 1 elem/thread).
// ---------------------------------------------------------------------------
__global__ __launch_bounds__(256) void k1_kernel(ConvArgs a, ush* __restrict__ dst,
                                                 ush* __restrict__ tw,
                                                 int* __restrict__ cnt_r1, CsrB c,
                                                 int* __restrict__ HB,
                                                 ush* __restrict__ weff) {
    const int b = blockIdx.x;
    if (b < NCONVB) {
        long g = (long)b * 256 + threadIdx.x;
        if (g >= (long)CW_TOTAL) return;
        int t = 0;
        while (g >= a.cum[t + 1]) t++;
        long i = g - a.cum[t];
        float v = a.fl[t] ? ((const float*)a.src[t])[i] : b2f(((const ush*)a.src[t])[i]);
        dst[g] = f2b(v);
    } else if (b < NCONVB + NZB) {
        int g = (b - NCONVB) * 256 + threadIdx.x;
        if (g < 100000) cnt_r1[g] = 0;
    } else if (b < NCONVB + NZB + NHIST) {
        __shared__ int h[5000];
        int r, E, ndst, e0, e1, hb;
        const int* ei;
        hist_geom(b - NCONVB - NZB, c, r, ei, E, ndst, e0, e1, hb);
        for (int d = threadIdx.x; d < ndst; d += 256) h[d] = 0;
        __syncthreads();
        for (int e = e0 + threadIdx.x; e < e1; e += 256) atomicAdd(&h[ei[E + e]], 1);
        __syncthreads();
        for (int d = threadIdx.x; d < ndst; d += 256) HB[hb + d] = h[d];
    } else if (b < NCONVB + NZB + NHIST + NTWB) {
        int g = (b - NCONVB - NZB - NHIST) * 256 + threadIdx.x;  // [0, 65536)
        const void* src; int fl; long ibase; int e;
        if (g < 4096) { src = a.src[0]; fl = a.fl[0]; e = g; ibase = 0; }
        else if (g < 12288) { src = a.src[2]; fl = a.fl[2]; e = g - 4096; ibase = 0; }
        else if (g < 16384) { src = a.src[4]; fl = a.fl[4]; e = g - 12288; ibase = 0; }
        else if (g < 40960) { int ee = g - 16384; src = a.src[8]; fl = a.fl[8];
                              e = ee & 4095; ibase = (long)(ee >> 12) * 4096; }
        else { int ee = g - 40960; src = a.src[12]; fl = a.fl[12];
               e = ee & 4095; ibase = (long)(ee >> 12) * 4096; }
        int f = e >> 9, l = (e >> 3) & 63, j = e & 7;
        int s = f >> 2, cc = f & 3;
        long in = ibase + (long)(32 * s + ((l >> 4) << 3) + j) * 64 + 16 * cc + (l & 15);
        float v = fl ? ((const float*)src)[in] : b2f(((const ush*)src)[in]);
        tw[g] = f2b(v);
    } else {
        // eff folding: 8*8320 elements, one per thread (no serial tail)
        int g = (b - NCONVB - NZB - NHIST - NTWB) * 256 + threadIdx.x;
        if (g >= 8 * 8320) return;
        const int eb = g / 8320;  // l*4+r
        const int idx = g % 8320;
        const int l = eb >> 2, r = eb & 3;
        const int st_of[4] = {0, 1, 1, 0};
        const int st = st_of[r];
        int k, n;
        if (idx < 8192) {
            int f = idx >> 9, ll = (idx >> 3) & 63, j = idx & 7;
            int s = f >> 3, cc = f & 7;
            k = 32 * s + ((ll >> 4) << 3) + j;
            n = 16 * cc + (ll & 15);
        } else { k = -1; n = idx - 8192; }
        int kv = n >= 64;
        int jj = n & 63, h = jj >> 4, e = jj & 15;
        const void* Wp = kv ? a.src[10] : a.src[6];
        const int flW = kv ? a.fl[10] : a.fl[6];
        const void* Bp = kv ? a.src[11] : a.src[7];
        const int flB = kv ? a.fl[11] : a.fl[7];
        const void* Rp = kv ? a.src[15] : a.src[14];
        const int flR = kv ? a.fl[15] : a.fl[14];
        const long wb = (long)(l * 3 + st) * 4096;
        const long bb = (long)(l * 3 + st) * 64;
        const long rb = (long)(l * 4 + r) * 1024;
        float acc = 0.f;
        if (k >= 0) {
#pragma unroll
            for (int d = 0; d < 16; d++)
                acc += ldr(Wp, flW, wb + k * 64 + h * 16 + d) *
                       ldr(Rp, flR, rb + h * 256 + d * 16 + e);
        } else {
#pragma unroll
            for (int d = 0; d < 16; d++)
                acc += ldr(Bp, flB, bb + h * 16 + d) *
                       ldr(Rp, flR, rb + h * 256 + d * 16 + e);
        }
        weff[(size_t)eb * 8320 + idx] = f2b(acc);
    }
}

// ---------------------------------------------------------------------------
// MFMA building blocks.
// ---------------------------------------------------------------------------
template <int K>
__device__ __forceinline__ void stage_A_raw(short* sA, const void* __restrict__ X, int f,
                                            int M, int row0) {
    for (int cid = threadIdx.x; cid < 64 * K / 8; cid += 256) {
        int r = cid / (K / 8), c0 = (cid % (K / 8)) * 8;
        int row = row0 + r;
        short8 v = {0, 0, 0, 0, 0, 0, 0, 0};
        if (row < M) {
            if (f) {
                const floatx4* fp = (const floatx4*)((const float*)X + (size_t)row * K + c0);
                floatx4 f0 = fp[0], f1 = fp[1];
#pragma unroll
                for (int j = 0; j < 4; j++) v[j] = (short)f2b(f0[j]);
#pragma unroll
                for (int j = 0; j < 4; j++) v[4 + j] = (short)f2b(f1[j]);
            } else {
                v = *(const short8*)(const void*)((const ush*)X + (size_t)row * K + c0);
            }
        }
        *(short8*)(&sA[r * (K + 8) + c0]) = v;
    }
}

// stage a 64-col half of a [M][128] raw tensor into sA (stride 72)
__device__ __forceinline__ void stage_A_half(short* sA, const void* __restrict__ X, int f,
                                             int M, int row0, int half) {
    for (int cid = threadIdx.x; cid < 512; cid += 256) {
        int r = cid >> 3, c0 = (cid & 7) * 8;
        int row = row0 + r;
        short8 v = {0, 0, 0, 0, 0, 0, 0, 0};
        if (row < M) {
            long off = (long)row * 128 + half * 64 + c0;
            if (f) {
                const floatx4* fp = (const floatx4*)((const float*)X + off);
                floatx4 f0 = fp[0], f1 = fp[1];
#pragma unroll
                for (int j = 0; j < 4; j++) v[j] = (short)f2b(f0[j]);
#pragma unroll
                for (int j = 0; j < 4; j++) v[4 + j] = (short)f2b(f1[j]);
            } else {
                v = *(const short8*)(const void*)((const ush*)X + off);
            }
        }
        *(short8*)(&sA[r * 72 + c0]) = v;
    }
}

// one K=64 MFMA pass: A from sA (stride 72), B frags from sB, accumulate.
__device__ __forceinline__ void mfma64_acc(const short* sA, const short* sB, floatx4* acc) {
    const int tid = threadIdx.x;
    const int w = tid >> 6, l = tid & 63;
#pragma unroll
    for (int s = 0; s < 2; s++) {
        short8 av = *(const short8*)(&sA[(16 * w + (l & 15)) * 72 + 32 * s + ((l >> 4) << 3)]);
#pragma unroll
        for (int c = 0; c < 4; c++) {
            short8 bv = *(const short8*)(&sB[(s * 4 + c) * 512 + l * 8]);
            acc[c] = __builtin_amdgcn_mfma_f32_16x16x32_bf16(av, bv, acc[c], 0, 0, 0);
        }
    }
}

// ---------------------------------------------------------------------------
// 5-panel streaming QKV gemm with double-buffered sB prefetch:
// A-fragments in registers (sA freed -> output stage); per panel
// {prefetch next B into alt sB half | 8 MFMAs | scatter | store}.
// sB region = 2 x 4096 shorts (16384 B). Barriers: 2/panel (was 3).
// Panels: 0=Q, 1=relA.K, 2=relA.V, 3=relB.K, 4=relB.V (all ld-64).
// ---------------------------------------------------------------------------
template <int NP>
__device__ __forceinline__ void gemm_panels(short* sA, short* sB,
                                            const ush* __restrict__ Wq,
                                            const ush* __restrict__ Bq, ush* __restrict__ Yq,
                                            const ush* __restrict__ WeA,
                                            ush* __restrict__ YAk, ush* __restrict__ YAv,
                                            const ush* __restrict__ WeB,
                                            ush* __restrict__ YBk, ush* __restrict__ YBv,
                                            int M, int row0) {
    const int tid = threadIdx.x;
    const int w = tid >> 6, l = tid & 63;
    __syncthreads();  // X-tile in sA visible
    short8 a0 = *(const short8*)(&sA[(16 * w + (l & 15)) * 72 + ((l >> 4) << 3)]);
    short8 a1 = *(const short8*)(&sA[(16 * w + (l & 15)) * 72 + 32 + ((l >> 4) << 3)]);
    ush* dst[5] = {Yq, YAk, YAv, YBk, YBv};
    // stage B[0] (always the Q panel) into sB half 0
    for (int u = tid; u < 512; u += 256) {
        int f = u >> 6, k = u & 63;
        int s = f >> 2, c = f & 3;
        const ush* src = Wq + (size_t)(s * 4 + c) * 512;
        *(short8*)(&sB[f * 512 + k * 8]) = *(const short8*)(const void*)(src + k * 8);
    }
    __syncthreads();  // B0 ready; a-regs loaded -> sA free for output staging
#pragma unroll
    for (int p = 0; p < NP; p++) {
        short* cur = sB + (p & 1) * 4096;
        short* nxt = sB + ((p + 1) & 1) * 4096;
        if (p + 1 < NP) {
            // prefetch B[p+1] (p+1 >= 1 -> always a KV panel, nw=8)
            const ush* base = ((p + 1) <= 2) ? WeA : WeB;
            const int moff = ((p + 1) == 1 || (p + 1) == 3) ? 0 : 4;
            for (int u = tid; u < 512; u += 256) {
                int f = u >> 6, k = u & 63;
                int s = f >> 2, c = f & 3;
                const ush* src = base + (size_t)(s * 8 + moff + c) * 512;
                *(short8*)(&nxt[f * 512 + k * 8]) = *(const short8*)(const void*)(src + k * 8);
            }
        }
        const ush* bias = (p == 0) ? Bq : ((p <= 2) ? WeA + 8192 : WeB + 8192);
        const int boff = (p == 0 || p == 1 || p == 3) ? 0 : 64;
        floatx4 acc[4];
#pragma unroll
        for (int c = 0; c < 4; c++) {
            float bv = b2f(bias[boff + 16 * c + (l & 15)]);
            acc[c] = (floatx4){bv, bv, bv, bv};
        }
#pragma unroll
        for (int c = 0; c < 4; c++) {
            short8 b0 = *(const short8*)(&cur[c * 512 + l * 8]);
            acc[c] = __builtin_amdgcn_mfma_f32_16x16x32_bf16(a0, b0, acc[c], 0, 0, 0);
            short8 b1 = *(const short8*)(&cur[(4 + c) * 512 + l * 8]);
            acc[c] = __builtin_amdgcn_mfma_f32_16x16x32_bf16(a1, b1, acc[c], 0, 0, 0);
        }
#pragma unroll
        for (int c = 0; c < 4; c++)
#pragma unroll
            for (int r = 0; r < 4; r++)
                sA[(16 * w + ((l >> 4) << 2) + r) * 72 + 16 * c + (l & 15)] =
                    (short)f2b(acc[c][r]);
        __syncthreads();  // scatter visible; next-B staged
        ush* Y = dst[p];
        for (int u = tid; u < 512; u += 256) {
            int r = u >> 3, c0 = (u & 7) * 8;
            int row = row0 + r;
            if (row < M)
                *(short8*)(Y + (size_t)row * 64 + c0) = *(const short8*)(&sA[r * 72 + c0]);
        }
        if (p + 1 < NP) __syncthreads();  // store reads done before next scatter
    }
}

__device__ __forceinline__ void run_panels(int t, short* sA, short* sB,
                                           const ush* const* Wq, const ush* const* Bq,
                                           const ush* const* We, ush* Q,
                                           ush* const* KVk, ush* const* KVv,
                                           int M, int row0) {
    if (t == 0)
        gemm_panels<5>(sA, sB, Wq[0], Bq[0], Q, We[0], KVk[0], KVv[0],
                       We[3], KVk[3], KVv[3], M, row0);
    else if (t == 1)
        gemm_panels<5>(sA, sB, Wq[1], Bq[1], Q + (size_t)N_P * 64, We[1], KVk[1], KVv[1],
                       We[2], KVk[2], KVv[2], M, row0);
    else
        gemm_panels<1>(sA, sB, Wq[2], Bq[2], Q + (size_t)(N_P + N_D) * 64,
                       nullptr, nullptr, nullptr, nullptr, nullptr, nullptr, M, row0);
}

// ---------------------------------------------------------------------------
// K2F: fused input projections + layer-0 Q/KV panels | chunk-scan | r1 counts.
// Dyn LDS: sA 9216 + sB 2x8192 = 25600 B (D's K=128 done as two K=64 halves).
// ---------------------------------------------------------------------------
struct K2FArgs {
    const void* raw[3];
    int f[3];
    const ush* Wi[3];  // inproj fragment weights (TW)
    const ush* Bi[3];  // inproj biases (CW)
    ush* X;
    const ush* Wq[3];  // layer-0 Q fragment weights (TW)
    const ush* Bq[3];
    const ush* We[4];  // layer-0 eff fragment weights (weff)
    ush* Q;
    ush* KVk[4];
    ush* KVv[4];
    const int* HB;
    int* CS;
    int* cnt;
    const int* ei1;
};

__global__ __launch_bounds__(256) void k2f_kernel(K2FArgs a) {
    extern __shared__ short smem[];
    const int b = blockIdx.x;
    if (b < 1658) {
        short* sA = smem;
        short* sB = smem + 64 * 72;
        const int tid = threadIdx.x;
        const int w = tid >> 6, l = tid & 63;
        int t, lb, M;
        if (b < 1563) { t = 0; lb = b; M = N_P; }
        else if (b < 1579) { t = 1; lb = b - 1563; M = N_D; }
        else { t = 2; lb = b - 1579; M = N_S; }
        const size_t noff = (t == 0) ? 0 : (t == 1) ? (size_t)N_P : (size_t)(N_P + N_D);
        const int row0 = lb * 64;
        floatx4 acc[4];
#pragma unroll
        for (int c = 0; c < 4; c++) {
            float bv = b2f(a.Bi[t][16 * c + (l & 15)]);
            acc[c] = (floatx4){bv, bv, bv, bv};
        }
        if (t != 1) {
            stage_A_raw<64>(sA, a.raw[t], a.f[t], M, row0);
            for (int u = tid; u < 512; u += 256)
                *(short8*)(&sB[u * 8]) = *(const short8*)(const void*)(a.Wi[t] + (size_t)u * 8);
            __syncthreads();
            mfma64_acc(sA, sB, acc);
        } else {
#pragma unroll
            for (int hh = 0; hh < 2; hh++) {
                if (hh) __syncthreads();  // prev MFMA reads done before restage
                stage_A_half(sA, a.raw[1], a.f[1], M, row0, hh);
                for (int u = tid; u < 512; u += 256)
                    *(short8*)(&sB[u * 8]) =
                        *(const short8*)(const void*)(a.Wi[1] + (size_t)hh * 4096 + (size_t)u * 8);
                __syncthreads();
                mfma64_acc(sA, sB, acc);
            }
        }
        __syncthreads();
        // scatter X tile into sA (72-stride)
#pragma unroll
        for (int c = 0; c < 4; c++)
#pragma unroll
            for (int r = 0; r < 4; r++)
                sA[(16 * w + ((l >> 4) << 2) + r) * 72 + 16 * c + (l & 15)] =
                    (short)f2b(acc[c][r]);
        __syncthreads();
        ush* Xb = a.X + noff * 64;
        for (int u = tid; u < 512; u += 256) {
            int r = u >> 3, c0 = (u & 7) * 8;
            int row = row0 + r;
            if (row < M)
                *(short8*)(Xb + (size_t)row * 64 + c0) = *(const short8*)(&sA[r * 72 + c0]);
        }
        run_panels(t, sA, sB, a.Wq, a.Bq, a.We, a.Q, a.KVk, a.KVv, M, row0);
    } else if (b < 1701) {
        int d = (b - 1658) * 256 + threadIdx.x;
        if (d >= 11000) return;
        int ld_, nch, base, step, cs0, csstep, roff;
        if (d < 1000) { ld_ = d; nch = NCH0; base = HB0_OFF + ld_; step = 1000;
                        cs0 = CS0_OFF + ld_; csstep = 1000; roff = 0; }
        else if (d < 6000) { ld_ = d - 1000; nch = NCH2; base = HB2_OFF + ld_; step = 5000;
                             cs0 = CS2_OFF + ld_; csstep = 5000; roff = 101000; }
        else { ld_ = d - 6000; nch = NCH2; base = HB3_OFF + ld_; step = 5000;
               cs0 = CS3_OFF + ld_; csstep = 5000; roff = 106000; }
        int run = 0;
        for (int cc = 0; cc < nch; cc++) {
            int s = 0;
#pragma unroll
            for (int bb = 0; bb < 16; bb++) s += a.HB[base + (cc * 16 + bb) * step];
            a.CS[cs0 + cc * csstep] = run;
            run += s;
        }
        a.cnt[roff + ld_] = run;
    } else {
        int g = (b - 1701) * 256 + threadIdx.x;
        if (g < 300000) atomicAdd(&a.cnt[1000 + a.ei1[300000 + g]], 1);
    }
}

// ---------------------------------------------------------------------------
// K3: scanA (block-local scan + partials) only.
// ---------------------------------------------------------------------------
__global__ __launch_bounds__(256) void k3_kernel(const int* __restrict__ cnt,
                                                 int* __restrict__ tmp,
                                                 int* __restrict__ part) {
    const int b = blockIdx.x;
    __shared__ int ls[256];
    const int t = threadIdx.x;
    const int base = b * 1024 + t * 4;
    int v[4];
#pragma unroll
    for (int j = 0; j < 4; j++) v[j] = (base + j < NC) ? cnt[base + j] : 0;
    int tsum = v[0] + v[1] + v[2] + v[3];
    ls[t] = tsum;
    __syncthreads();
    for (int off = 1; off < 256; off <<= 1) {
        int y = (t >= off) ? ls[t - off] : 0;
        __syncthreads();
        ls[t] += y;
        __syncthreads();
    }
    int run = ls[t] - tsum;
#pragma unroll
    for (int j = 0; j < 4; j++) {
        if (base + j < NC) tmp[base + j] = run;
        run += v[j];
    }
    if (t == 255) part[b] = ls[255];
}

// ---------------------------------------------------------------------------
// K4: rowptr (inline partial rescan) | fixHB | zero fillpos.
// ---------------------------------------------------------------------------
__global__ __launch_bounds__(256) void k4_kernel(const int* __restrict__ tmp,
                                                 const int* __restrict__ part,
                                                 int* __restrict__ rowptr,
                                                 int* __restrict__ HB,
                                                 const int* __restrict__ CS,
                                                 int* __restrict__ fillpos) {
    const int b = blockIdx.x;
    if (b < NSCB) {
        __shared__ int ls[256];
        const int t = threadIdx.x;
        ls[t] = (t < 109) ? part[t] : 0;
        __syncthreads();
        for (int off = 1; off < 256; off <<= 1) {
            int y = (t >= off) ? ls[t - off] : 0;
            __syncthreads();
            ls[t] += y;
            __syncthreads();
        }
        int i = b * 256 + t;
        if (i <= NC)
            rowptr[i] = (i == NC) ? ls[255] : tmp[i] + ((i >> 10) ? ls[(i >> 10) - 1] : 0);
    } else if (b < NSCB + 188) {
        int g = (b - NSCB) * 256 + threadIdx.x;
        int idx0, step;
        if (!cs_geom(g, idx0, step)) return;
        int run = CS[g];
#pragma unroll
        for (int bb = 0; bb < 16; bb++) {
            int t2 = HB[idx0 + bb * step];
            HB[idx0 + bb * step] = run;
            run += t2;
        }
    } else {
        int g = (b - NSCB - 188) * 256 + threadIdx.x;
        if (g < 100000) fillpos[g] = 0;
    }
}

// ---------------------------------------------------------------------------
// fill: CSR column fill (layer 0 only). Dyn LDS: 20000 B.
// ---------------------------------------------------------------------------
struct FillArgs {
    CsrB cb;
    const int* HB;
    const int* rowptr;
    int* fillpos;  // == CNT base; kernel indexes fillpos[1000 + dst]
    int* col;
};

__global__ __launch_bounds__(256) void fill_kernel(FillArgs a) {
    extern __shared__ short smem[];
    const int b = blockIdx.x;
    if (b < NHIST) {
        int* h = (int*)smem;
        int r, E, ndst, e0, e1, hb;
        const int* ei;
        hist_geom(b, a.cb, r, ei, E, ndst, e0, e1, hb);
        const int roff = (r == 0) ? 0 : (r == 1) ? 101000 : 106000;
        for (int d = threadIdx.x; d < ndst; d += 256) h[d] = a.rowptr[roff + d] + a.HB[hb + d];
        __syncthreads();
        for (int e = e0 + threadIdx.x; e < e1; e += 256) {
            int d = ei[E + e];
            int slot = atomicAdd(&h[d], 1);
            a.col[slot] = ei[e];
        }
    } else {
        int g = (b - NHIST) * 256 + threadIdx.x;
        if (g < 300000) {
            int gi = 1000 + a.cb.ei1[300000 + g];
            int slot = a.rowptr[gi] + atomicAdd(&a.fillpos[gi], 1);
            a.col[slot] = a.cb.ei1[g];
        }
    }
}

// ---------------------------------------------------------------------------
// Fused gather aggregation; K/V in split half-arrays; writes gelu(out) bf16.
// Fixed per-lane shift softmax (peeled first edge) -> independent iterations;
// unroll-2 software pipeline for MLP.
// ---------------------------------------------------------------------------
struct AggrArgs {
    const int* rowptr;
    const int* col;
    const ush* KVk[4];
    const ush* KVv[4];
    const ush* Q;
    const ush* prel;
    ush* OUT;
};

template <int LANES>
__device__ __forceinline__ void seg_attn(const AggrArgs& a, int rel, int g, int h, int lane,
                                         const float* qf, float* o) {
    const int s0 = a.rowptr[g], s1 = a.rowptr[g + 1];
    const ush* Kb = a.KVk[rel];
    const ush* Vb = a.KVv[rel];
    const float ps = b2f(a.prel[rel * 4 + h]) * 0.25f;
    float m = -1e30f, s = 0.f;
    float acc[16];
#pragma unroll
    for (int i = 0; i < 16; i++) acc[i] = 0.f;
    int j = s0 + lane;
    if (j < s1) {
        {
            int src = a.col[j];
            const ush* kp = Kb + (size_t)src * 64 + h * 16;
            const ush* vp = Vb + (size_t)src * 64 + h * 16;
            short8 k0 = *(const short8*)(const void*)kp;
            short8 k1 = *(const short8*)(const void*)(kp + 8);
            short8 v0 = *(const short8*)(const void*)vp;
            short8 v1 = *(const short8*)(const void*)(vp + 8);
            float dot = 0.f;
#pragma unroll
            for (int i = 0; i < 8; i++) dot += qf[i] * b2f((ush)k0[i]);
#pragma unroll
            for (int i = 0; i < 8; i++) dot += qf[8 + i] * b2f((ush)k1[i]);
            m = dot * ps;
            s = 1.f;
#pragma unroll
            for (int i = 0; i < 8; i++) acc[i] = b2f((ush)v0[i]);
#pragma unroll
            for (int i = 0; i < 8; i++) acc[8 + i] = b2f((ush)v1[i]);
        }
        j += LANES;
        for (; j + LANES < s1; j += 2 * LANES) {
            int srcA = a.col[j];
            int srcB = a.col[j + LANES];
            const ush* kpA = Kb + (size_t)srcA * 64 + h * 16;
            const ush* vpA = Vb + (size_t)srcA * 64 + h * 16;
            const ush* kpB = Kb + (size_t)srcB * 64 + h * 16;
            const ush* vpB = Vb + (size_t)srcB * 64 + h * 16;
            short8 k0A = *(const short8*)(const void*)kpA;
            short8 k1A = *(const short8*)(const void*)(kpA + 8);
            short8 v0A = *(const short8*)(const void*)vpA;
            short8 v1A = *(const short8*)(const void*)(vpA + 8);
            short8 k0B = *(const short8*)(const void*)kpB;
            short8 k1B = *(const short8*)(const void*)(kpB + 8);
            short8 v0B = *(const short8*)(const void*)vpB;
            short8 v1B = *(const short8*)(const void*)(vpB + 8);
            float dotA = 0.f, dotB = 0.f;
#pragma unroll
            for (int i = 0; i < 8; i++) dotA += qf[i] * b2f((ush)k0A[i]);
#pragma unroll
            for (int i = 0; i < 8; i++) dotA += qf[8 + i] * b2f((ush)k1A[i]);
#pragma unroll
            for (int i = 0; i < 8; i++) dotB += qf[i] * b2f((ush)k0B[i]);
#pragma unroll
            for (int i = 0; i < 8; i++) dotB += qf[8 + i] * b2f((ush)k1B[i]);
            float eA = __expf(dotA * ps - m);
            float eB = __expf(dotB * ps - m);
            s += eA + eB;
#pragma unroll
            for (int i = 0; i < 8; i++) acc[i] += eA * b2f((ush)v0A[i]) + eB * b2f((ush)v0B[i]);
#pragma unroll
            for (int i = 0; i < 8; i++)
                acc[8 + i] += eA * b2f((ush)v1A[i]) + eB * b2f((ush)v1B[i]);
        }
        if (j < s1) {
            int src = a.col[j];
            const ush* kp = Kb + (size_t)src * 64 + h * 16;
            const ush* vp = Vb + (size_t)src * 64 + h * 16;
            short8 k0 = *(const short8*)(const void*)kp;
            short8 k1 = *(const short8*)(const void*)(kp + 8);
            short8 v0 = *(const short8*)(const void*)vp;
            short8 v1 = *(const short8*)(const void*)(vp + 8);
            float dot = 0.f;
#pragma unroll
            for (int i = 0; i < 8; i++) dot += qf[i] * b2f((ush)k0[i]);
#pragma unroll
            for (int i = 0; i < 8; i++) dot += qf[8 + i] * b2f((ush)k1[i]);
            float e1 = __expf(dot * ps - m);
            s += e1;
#pragma unroll
            for (int i = 0; i < 8; i++) acc[i] += e1 * b2f((ush)v0[i]);
#pragma unroll
            for (int i = 0; i < 8; i++) acc[8 + i] += e1 * b2f((ush)v1[i]);
        }
    }
#pragma unroll
    for (int wd = LANES >> 1; wd >= 1; wd >>= 1) {
        float mo = __shfl_xor(m, wd);
        float so = __shfl_xor(s, wd);
        float nm = fmaxf(m, mo);
        float e0 = __expf(m - nm), e1 = __expf(mo - nm);
        s = s * e0 + so * e1;
#pragma unroll
        for (int i = 0; i < 16; i++) {
            float ao = __shfl_xor(acc[i], wd);
            acc[i] = acc[i] * e0 + ao * e1;
        }
        m = nm;
    }
    float inv = 1.f / (s + 1e-16f);
#pragma unroll
    for (int i = 0; i < 16; i++) o[i] += acc[i] * inv;
}

template <int LANES>
__device__ __forceinline__ void job_run(const AggrArgs& a, int wid, int nd, int rel, int roff,
                                        size_t xoff, int rel2, int roff2) {
    const int lane = wid % LANES;
    const int grp = wid / LANES;
    const int d = grp >> 2, h = grp & 3;
    if (d >= nd) return;
    const ush* qp = a.Q + xoff + (size_t)d * 64 + h * 16;
    short8 q0 = *(const short8*)(const void*)qp;
    short8 q1 = *(const short8*)(const void*)(qp + 8);
    float qf[16];
#pragma unroll
    for (int i = 0; i < 8; i++) { qf[i] = b2f((ush)q0[i]); qf[8 + i] = b2f((ush)q1[i]); }
    float o[16];
#pragma unroll
    for (int i = 0; i < 16; i++) o[i] = 0.f;
    seg_attn<LANES>(a, rel, roff + d, h, lane, qf, o);
    if (rel2 >= 0) seg_attn<LANES>(a, rel2, roff2 + d, h, lane, qf, o);
    if (lane == 0) {
        ush* op = a.OUT + xoff + (size_t)d * 64 + h * 16;
        short8 w0, w1;
#pragma unroll
        for (int i = 0; i < 8; i++) {
            float va = o[i];
            w0[i] = (short)f2b(0.5f * va * (1.0f + erff(va * 0.70710678118654752f)));
            float vb = o[8 + i];
            w1[i] = (short)f2b(0.5f * vb * (1.0f + erff(vb * 0.70710678118654752f)));
        }
        *(short8*)(op) = w0;
        *(short8*)(op + 8) = w1;
    }
}

// blocks: [0,250) drugs L=16 | [250,563) diseases L=4 | [563,3688) patients L=2
__global__ __launch_bounds__(256) void aggr_kernel(AggrArgs a) {
    const int b = blockIdx.x, t = threadIdx.x;
    if (b < 250) {
        job_run<16>(a, b * 256 + t, N_D, 0, 0, (size_t)N_P * 64, -1, 0);
    } else if (b < 563) {
        job_run<4>(a, (b - 250) * 256 + t, N_S, 2, 101000, (size_t)(N_P + N_D) * 64, 3, 106000);
    } else {
        job_run<2>(a, (b - 563) * 256 + t, N_P, 1, 1000, 0, -1, 0);
    }
}

// ---------------------------------------------------------------------------
// Epi0 (layer 0, fused with layer-1 Q/KV panels). Dyn LDS 25600 B.
// ---------------------------------------------------------------------------
struct Epi0Args {
    const ush* O;
    ush* X;
    const ush* Wa[3];  // layer-0 epilogue weights (TWA, fragment)
    const ush* Ba[3];
    const ush* skipv;  // layer-0 skip
    const ush* Wq[3];  // layer-1 Q weights (TW, fragment)
    const ush* Bq[3];
    const ush* We[4];  // layer-1 eff weights (weff, fragment)
    ush* Q;
    ush* KVk[4];
    ush* KVv[4];
};

__global__ __launch_bounds__(256) void epi0_kernel(Epi0Args a) {
    extern __shared__ short smem[];
    short* sA = smem;
    short* sB = smem + 64 * 72;
    const int b = blockIdx.x;
    int t, lb, M;
    size_t noff;
    if (b < 1563) { t = 0; lb = b; M = N_P; noff = 0; }
    else if (b < 1579) { t = 1; lb = b - 1563; M = N_D; noff = (size_t)N_P; }
    else { t = 2; lb = b - 1579; M = N_S; noff = (size_t)(N_P + N_D); }
    const ush* O = a.O + noff * 64;
    ush* X = a.X + noff * 64;
    const int tid = threadIdx.x;
    const int w = tid >> 6, l = tid & 63;
    const int row0 = lb * 64;
    for (int u = tid; u < 512; u += 256) {
        int r = u >> 3, c0 = (u & 7) * 8;
        int row = row0 + r;
        short8 sv = {0, 0, 0, 0, 0, 0, 0, 0};
        if (row < M) sv = *(const short8*)(const void*)(O + (size_t)row * 64 + c0);
        *(short8*)(&sA[r * 72 + c0]) = sv;
    }
    for (int u = tid; u < 512; u += 256)
        *(short8*)(&sB[u * 8]) = *(const short8*)(const void*)(a.Wa[t] + (size_t)u * 8);
    __syncthreads();
    floatx4 acc[4];
#pragma unroll
    for (int c = 0; c < 4; c++) {
        float bv = b2f(a.Ba[t][16 * c + (l & 15)]);
        acc[c] = (floatx4){bv, bv, bv, bv};
    }
    mfma64_acc(sA, sB, acc);
    __syncthreads();
    // old X tile -> sA (coalesced)
    for (int u = tid; u < 512; u += 256) {
        int r = u >> 3, c0 = (u & 7) * 8;
        int row = row0 + r;
        if (row < M)
            *(short8*)(&sA[r * 72 + c0]) =
                *(const short8*)(const void*)(X + (size_t)row * 64 + c0);
    }
    __syncthreads();
    const float sg = 1.f / (1.f + expf(-b2f(a.skipv[t])));
#pragma unroll
    for (int c = 0; c < 4; c++)
#pragma unroll
        for (int r = 0; r < 4; r++) {
            int rr = 16 * w + ((l >> 4) << 2) + r;
            int cc = 16 * c + (l & 15);
            float val = sg * acc[c][r] + (1.f - sg) * b2f((ush)sA[rr * 72 + cc]);
            sA[rr * 72 + cc] = (short)f2b(val);
        }
    __syncthreads();
    for (int u = tid; u < 512; u += 256) {
        int r = u >> 3, c0 = (u & 7) * 8;
        int row = row0 + r;
        if (row < M)
            *(short8*)(X + (size_t)row * 64 + c0) = *(const short8*)(&sA[r * 72 + c0]);
    }
    run_panels(t, sA, sB, a.Wq, a.Bq, a.We, a.Q, a.KVk, a.KVv, M, row0);
}

// ---------------------------------------------------------------------------
// Final epilogue (layer 1): x_out = s*(OUT @ Wa + ba) + (1-s)*x, fp32/bf16 out.
// ---------------------------------------------------------------------------
struct EpiArgs {
    const ush* O;
    ush* X;
    const ush* W[3];
    const ush* Bb[3];
    const ush* skipv;
    void* fout;
    int foutf;  // 1 = final output fp32, 0 = bf16
    int last;
};

__global__ __launch_bounds__(256) void epi_kernel(EpiArgs a) {
    const int b = blockIdx.x;
    int t, lb, M;
    size_t noff;
    if (b < 1563) { t = 0; lb = b; M = N_P; noff = 0; }
    else if (b < 1579) { t = 1; lb = b - 1563; M = N_D; noff = (size_t)N_P; }
    else { t = 2; lb = b - 1579; M = N_S; noff = (size_t)(N_P + N_D); }
    const ush* O = a.O + noff * 64;
    ush* X = a.X + noff * 64;
    const ush* WF = a.W[t];
    __shared__ short sA[64 * 72];  // reused as fp32 stage (32 x 68 floats)
    __shared__ short sB[8 * 512];
    const int tid = threadIdx.x;
    const int row0 = lb * 64;
    for (int cid = tid; cid < 512; cid += 256) {
        int r = cid >> 3, c0 = (cid & 7) * 8;
        int row = row0 + r;
        short8 sv = {0, 0, 0, 0, 0, 0, 0, 0};
        if (row < M) sv = *(const short8*)(const void*)(O + (size_t)row * 64 + c0);
        *(short8*)(&sA[r * 72 + c0]) = sv;
    }
    for (int u = tid; u < 512; u += 256)
        *(short8*)(&sB[u * 8]) = *(const short8*)(const void*)(WF + (size_t)u * 8);
    __syncthreads();
    const float sg = 1.f / (1.f + expf(-b2f(a.skipv[t])));
    const int w = tid >> 6, l = tid & 63;
    floatx4 acc[4];
#pragma unroll
    for (int c = 0; c < 4; c++) {
        float bv = b2f(a.Bb[t][16 * c + (l & 15)]);
        acc[c] = (floatx4){bv, bv, bv, bv};
    }
#pragma unroll
    for (int s = 0; s < 2; s++) {
        short8 av = *(const short8*)(&sA[(16 * w + (l & 15)) * 72 + 32 * s + ((l >> 4) << 3)]);
#pragma unroll
        for (int c = 0; c < 4; c++) {
            short8 bv = *(const short8*)(&sB[(s * 4 + c) * 512 + l * 8]);
            acc[c] = __builtin_amdgcn_mfma_f32_16x16x32_bf16(av, bv, acc[c], 0, 0, 0);
        }
    }
    float* sOf = (float*)sA;
#pragma unroll
    for (int ch = 0; ch < 2; ch++) {
        __syncthreads();
        if ((w >> 1) == ch) {
#pragma unroll
            for (int c = 0; c < 4; c++)
#pragma unroll
                for (int r = 0; r < 4; r++)
                    sOf[(16 * (w & 1) + ((l >> 4) << 2) + r) * 68 + 16 * c + (l & 15)] =
                        acc[c][r];
        }
        __syncthreads();
        {
            int r = tid >> 3, c0 = (tid & 7) * 8;
            int row = row0 + ch * 32 + r;
            if (row < M) {
                floatx4 f0 = *(const floatx4*)(&sOf[r * 68 + c0]);
                floatx4 f1 = *(const floatx4*)(&sOf[r * 68 + c0 + 4]);
                short8 xv = *(const short8*)(const void*)(X + (size_t)row * 64 + c0);
                float vo[8];
#pragma unroll
                for (int j = 0; j < 4; j++) vo[j] = sg * f0[j] + (1.f - sg) * b2f((ush)xv[j]);
#pragma unroll
                for (int j = 0; j < 4; j++)
                    vo[4 + j] = sg * f1[j] + (1.f - sg) * b2f((ush)xv[4 + j]);
                if (!a.last) {
                    short8 ov;
#pragma unroll
                    for (int j = 0; j < 8; j++) ov[j] = (short)f2b(vo[j]);
                    *(short8*)(X + (size_t)row * 64 + c0) = ov;
                } else {
                    size_t goff = (noff + row) * 64 + c0;
                    if (a.foutf) {
                        floatx4 o0, o1;
#pragma unroll
                        for (int j = 0; j < 4; j++) { o0[j] = vo[j]; o1[j] = vo[4 + j]; }
                        *(floatx4*)((float*)a.fout + goff) = o0;
                        *(floatx4*)((float*)a.fout + goff + 4) = o1;
                    } else {
                        short8 ov;
#pragma unroll
                        for (int j = 0; j < 8; j++) ov[j] = (short)f2b(vo[j]);
                        *(short8*)((ush*)a.fout + goff) = ov;
                    }
                }
            }
        }
    }
}

// ---------------------------------------------------------------------------
extern "C" void kernel_launch(void* const* d_in, const int* in_sizes, int n_in,
                              void* d_out, int out_size, void* d_ws, size_t ws_size,
                              hipStream_t stream) {
    // ---- Workspace layout ----
    char* w = (char*)d_ws;
    w += 64;
    ush* CW = (ush*)w;      w += ((CW_TOTAL * 2 + 63) / 64) * 64;
    ush* WEFFB = (ush*)w;   w += ((size_t)8 * 8320 * 2 + 63) / 64 * 64;
    ush* TW = (ush*)w;      w += (size_t)TW_TOTAL * 2;
    ush* X = (ush*)w;       w += (size_t)NT * 64 * 2;
    ush* Q = (ush*)w;       w += (size_t)NT * 64 * 2;
    ush* KV0 = (ush*)w;     w += (size_t)N_P * 128 * 2;
    ush* KV1 = (ush*)w;     w += (size_t)N_D * 128 * 2;
    ush* KV2 = (ush*)w;     w += (size_t)N_D * 128 * 2;
    ush* KV3 = (ush*)w;     w += (size_t)N_P * 128 * 2;
    ush* OUT = (ush*)w;     w += (size_t)NT * 64 * 4;  // fp32-size slab: HB/CS overlay below
    int* CNT = (int*)w;     w += (size_t)NC * 4;  // r1 region doubles as fillpos
    int* TMP = (int*)w;     w += (size_t)NC * 4;
    int* PART = (int*)w;    w += 512;
    int* ROWPTR = (int*)w;  w += (size_t)(NC + 1) * 4;
    int* COL = (int*)w;     w += (size_t)E_TOT * 4;
    int* HB = (int*)OUT;           // 768000 ints, dead before aggr
    int* CS = (int*)OUT + 800000;  // 48000 ints, same overlay

    // dtype flags from byte sizes (bytes == 2*elems -> bf16, else fp32)
    static const long sz[18] = {4096, 64, 8192, 64, 4096, 64, 24576, 384, 24576, 384,
                                24576, 384, 24576, 384, 8192, 8192, 32, 6};
    ConvArgs ca;
    long cum = 0;
    for (int t = 0; t < 18; t++) {
        ca.src[t] = d_in[3 + t];
        ca.cum[t] = cum;
        ca.fl[t] = (in_sizes[3 + t] != (int)(sz[t] * 2)) ? 1 : 0;
        cum += sz[t];
    }
    ca.cum[18] = cum;

    CsrB cb;
    cb.ei[0] = (const int*)d_in[21];
    cb.ei[1] = (const int*)d_in[23];
    cb.ei[2] = (const int*)d_in[24];
    cb.ei1 = (const int*)d_in[22];

    // K1: convert | zero CNT r1 | histograms | fragment transposes | eff folding
    k1_kernel<<<NCONVB + NZB + NHIST + NTWB + NEFFB, 256, 0, stream>>>(ca, CW, TW, CNT + 1000,
                                                                       cb, HB, WEFFB);

    ush* KVr[4] = {KV0, KV1, KV2, KV3};
    const size_t nsr[4] = {(size_t)N_P, (size_t)N_D, (size_t)N_D, (size_t)N_P};
    const int foutf = (out_size != NT * 64 * 2) ? 1 : 0;

    // K2F: inproj + layer-0 Q/KV panels | chunk-scan | r1 degree counts
    K2FArgs k2;
    k2.raw[0] = d_in[0]; k2.f[0] = (in_sizes[0] != N_P * 64 * 2) ? 1 : 0;
    k2.raw[1] = d_in[1]; k2.f[1] = (in_sizes[1] != N_D * 128 * 2) ? 1 : 0;
    k2.raw[2] = d_in[2]; k2.f[2] = (in_sizes[2] != N_S * 64 * 2) ? 1 : 0;
    k2.Wi[0] = TW + TWINP; k2.Bi[0] = CW + OFF_BINP;
    k2.Wi[1] = TW + TWIND; k2.Bi[1] = CW + OFF_BIND;
    k2.Wi[2] = TW + TWINS; k2.Bi[2] = CW + OFF_BINS;
    k2.X = X;
    for (int t = 0; t < 3; t++) {
        k2.Wq[t] = TW + TWQO + (size_t)(0 * 3 + t) * 4096;
        k2.Bq[t] = CW + OFF_BQ + (0 * 3 + t) * 64;
    }
    for (int r = 0; r < 4; r++) {
        k2.We[r] = WEFFB + (size_t)(0 * 4 + r) * 8320;
        k2.KVk[r] = KVr[r];
        k2.KVv[r] = KVr[r] + nsr[r] * 64;
    }
    k2.Q = Q;
    k2.HB = HB; k2.CS = CS; k2.cnt = CNT; k2.ei1 = cb.ei1;
    k2f_kernel<<<1701 + NBLK_R1, 256, 25600, stream>>>(k2);

    // K3: scanA
    k3_kernel<<<109, 256, 0, stream>>>(CNT, TMP, PART);

    // K4: rowptr | fixHB | zero fillpos
    k4_kernel<<<NSCB + 188 + NZB, 256, 0, stream>>>(TMP, PART, ROWPTR, HB, CS, CNT + 1000);

    // fill: CSR column fill
    FillArgs fa;
    fa.cb = cb;
    fa.HB = HB;
    fa.rowptr = ROWPTR;
    fa.fillpos = CNT;  // kernel indexes fillpos[1000+dst] -> CNT[1000..101000)
    fa.col = COL;
    fill_kernel<<<NHIST + NBLK_R1, 256, 20000, stream>>>(fa);

    // layer 0 aggregation
    AggrArgs aa;
    aa.rowptr = ROWPTR;
    aa.col = COL;
    for (int r = 0; r < 4; r++) {
        aa.KVk[r] = KVr[r];
        aa.KVv[r] = KVr[r] + nsr[r] * 64;
    }
    aa.Q = Q;
    aa.prel = CW + OFF_PREL + 0 * 16;
    aa.OUT = OUT;
    aggr_kernel<<<3688, 256, 0, stream>>>(aa);

    // layer-0 epilogue fused with layer-1 Q/KV panels
    Epi0Args e0;
    e0.O = OUT;
    e0.X = X;
    for (int t = 0; t < 3; t++) {
        e0.Wa[t] = TW + TWAO + (size_t)(0 * 3 + t) * 4096;
        e0.Ba[t] = CW + OFF_BA + (0 * 3 + t) * 64;
        e0.Wq[t] = TW + TWQO + (size_t)(1 * 3 + t) * 4096;
        e0.Bq[t] = CW + OFF_BQ + (1 * 3 + t) * 64;
    }
    e0.skipv = CW + OFF_SKIP + 0 * 3;
    for (int r = 0; r < 4; r++) {
        e0.We[r] = WEFFB + (size_t)(1 * 4 + r) * 8320;
        e0.KVk[r] = KVr[r];
        e0.KVv[r] = KVr[r] + nsr[r] * 64;
    }
    e0.Q = Q;
    epi0_kernel<<<1658, 256, 25600, stream>>>(e0);

    // layer 1 aggregation
    aa.prel = CW + OFF_PREL + 1 * 16;
    aggr_kernel<<<3688, 256, 0, stream>>>(aa);

    // final epilogue (layer 1)
    EpiArgs ea;
    ea.O = OUT;
    ea.X = X;
    for (int t = 0; t < 3; t++) {
        ea.W[t] = TW + TWAO + (size_t)(1 * 3 + t) * 4096;
        ea.Bb[t] = CW + OFF_BA + (1 * 3 + t) * 64;
    }
    ea.skipv = CW + OFF_SKIP + 1 * 3;
    ea.fout = d_out;
    ea.foutf = foutf;
    ea.last = 1;
    epi_kernel<<<1658, 256, 0, stream>>>(ea);
}